// Round 1
// baseline (893.228 us; speedup 1.0000x reference)
//
#include <hip/hip_runtime.h>
#include <math.h>

#define NG 64          // graphs
#define F_IN 128
#define NEG_SLOPE 0.2f

// ---------- helpers ----------
static __device__ __forceinline__ float elu_f(float x) { return x > 0.f ? x : expm1f(x); }
static __device__ __forceinline__ float lrelu(float x) { return x > 0.f ? x : NEG_SLOPE * x; }
static __device__ __forceinline__ unsigned enc_f32(float x) {
    unsigned u = __float_as_uint(x);
    return (u & 0x80000000u) ? ~u : (u | 0x80000000u);
}
static __device__ __forceinline__ float dec_f32(unsigned u) {
    unsigned b = (u & 0x80000000u) ? (u & 0x7fffffffu) : ~u;
    return __uint_as_float(b);
}

// ---------- CSR build ----------
__global__ void hist_kernel(const int* __restrict__ ei, int* __restrict__ cnt, int E, int N) {
    int e = blockIdx.x * blockDim.x + threadIdx.x;
    int ET = E + N;
    if (e >= ET) return;
    int dst = (e < E) ? ei[E + e] : (e - E);   // self-loops appended
    atomicAdd(&cnt[dst], 1);
}

// block scans 1024 elements (256 thr x 4), writes local-exclusive scan + block sum
__global__ void scan1_kernel(const int* __restrict__ cnt, int* __restrict__ excl,
                             int* __restrict__ bsum, int n) {
    __shared__ int sm[256];
    int t = threadIdx.x;
    int base = blockIdx.x * 1024 + t * 4;
    int v[4];
    #pragma unroll
    for (int u = 0; u < 4; ++u) { int idx = base + u; v[u] = (idx < n) ? cnt[idx] : 0; }
    int tsum = v[0] + v[1] + v[2] + v[3];
    sm[t] = tsum;
    __syncthreads();
    for (int off = 1; off < 256; off <<= 1) {
        int y = (t >= off) ? sm[t - off] : 0;
        __syncthreads();
        sm[t] += y;
        __syncthreads();
    }
    int run = sm[t] - tsum;  // exclusive base for this thread
    #pragma unroll
    for (int u = 0; u < 4; ++u) {
        int idx = base + u;
        if (idx < n) excl[idx] = run;
        run += v[u];
    }
    if (t == 255) bsum[blockIdx.x] = sm[255];
}

__global__ void scan2_kernel(int* __restrict__ bsum, int* __restrict__ offs, int nb, int n) {
    if (blockIdx.x == 0 && threadIdx.x == 0) {
        int run = 0;
        for (int b = 0; b < nb; ++b) { int t = bsum[b]; bsum[b] = run; run += t; }
        offs[n] = run;  // grand total = E + N
    }
}

__global__ void scan3_kernel(int* __restrict__ offs, const int* __restrict__ bsum, int n) {
    int base = blockIdx.x * 1024 + threadIdx.x * 4;
    int add = bsum[blockIdx.x];
    #pragma unroll
    for (int u = 0; u < 4; ++u) { int idx = base + u; if (idx < n) offs[idx] += add; }
}

__global__ void scatter_kernel(const int* __restrict__ ei, const int* __restrict__ offs,
                               int* __restrict__ cursor, int* __restrict__ csr_src, int E, int N) {
    int e = blockIdx.x * blockDim.x + threadIdx.x;
    int ET = E + N;
    if (e >= ET) return;
    int src, dst;
    if (e < E) { src = ei[e]; dst = ei[E + e]; }
    else       { src = e - E; dst = e - E; }
    int pos = offs[dst] + atomicAdd(&cursor[dst], 1);
    csr_src[pos] = src;
}

// ---------- f32 tiled GEMM: Out[n][m] = dot(A[n][:K], W[m][:K]) + bias[m] ----------
// grid: (ceil(N/64), M/64), block 256. LDS chunks stored K-major for float4 reads.
template<int K>
__global__ __launch_bounds__(256) void gemm_f32(const float* __restrict__ A,
                                                const float* __restrict__ W,
                                                float* __restrict__ Out,
                                                int N, int M, const float* __restrict__ bias) {
    __shared__ __align__(16) float As[32][68];
    __shared__ __align__(16) float Bs[32][68];
    const int t = threadIdx.x;
    const int n0 = blockIdx.x * 64;
    const int m0 = blockIdx.y * 64;
    const int i = t >> 4, j = t & 15;
    float acc[4][4] = {};
    for (int kc = 0; kc < K; kc += 32) {
        __syncthreads();
        for (int l = t; l < 512; l += 256) {
            int row = l >> 3, q = l & 7;
            int gr = n0 + row;
            float4 av = make_float4(0.f, 0.f, 0.f, 0.f);
            if (gr < N) av = *(const float4*)&A[(size_t)gr * K + kc + 4 * q];
            As[4 * q + 0][row] = av.x; As[4 * q + 1][row] = av.y;
            As[4 * q + 2][row] = av.z; As[4 * q + 3][row] = av.w;
            float4 bv = *(const float4*)&W[(size_t)(m0 + row) * K + kc + 4 * q];
            Bs[4 * q + 0][row] = bv.x; Bs[4 * q + 1][row] = bv.y;
            Bs[4 * q + 2][row] = bv.z; Bs[4 * q + 3][row] = bv.w;
        }
        __syncthreads();
        #pragma unroll
        for (int k = 0; k < 32; ++k) {
            float4 av = *(const float4*)&As[k][4 * i];
            float4 bv = *(const float4*)&Bs[k][4 * j];
            float a[4] = {av.x, av.y, av.z, av.w};
            float b[4] = {bv.x, bv.y, bv.z, bv.w};
            #pragma unroll
            for (int r = 0; r < 4; ++r)
                #pragma unroll
                for (int c = 0; c < 4; ++c) acc[r][c] = fmaf(a[r], b[c], acc[r][c]);
        }
    }
    float4 bias4 = make_float4(0.f, 0.f, 0.f, 0.f);
    if (bias) bias4 = *(const float4*)&bias[m0 + 4 * j];
    #pragma unroll
    for (int r = 0; r < 4; ++r) {
        int gr = n0 + 4 * i + r;
        if (gr < N) {
            float4 o;
            o.x = acc[r][0] + bias4.x; o.y = acc[r][1] + bias4.y;
            o.z = acc[r][2] + bias4.z; o.w = acc[r][3] + bias4.w;
            *(float4*)&Out[(size_t)gr * M + m0 + 4 * j] = o;
        }
    }
}

// ---------- attention scalars: s[n][h] = dot(h[n,h,:], a_src[h]) ----------
template<int H>
__global__ void attn_sd(const float* __restrict__ hL,
                        const float* __restrict__ a_src, const float* __restrict__ a_dst,
                        float* __restrict__ s, float* __restrict__ d, int N) {
    int w = (blockIdx.x * blockDim.x + threadIdx.x) >> 6;
    int lane = threadIdx.x & 63;
    if (w >= N) return;
    const float* hrow = hL + (size_t)w * (H * 64);
    #pragma unroll
    for (int h = 0; h < H; ++h) {
        float hv = hrow[h * 64 + lane];
        float ps = hv * a_src[h * 64 + lane];
        float pd = hv * a_dst[h * 64 + lane];
        #pragma unroll
        for (int off = 32; off; off >>= 1) {
            ps += __shfl_xor(ps, off);
            pd += __shfl_xor(pd, off);
        }
        if (lane == 0) { s[w * H + h] = ps; d[w * H + h] = pd; }
    }
}

// ---------- GAT aggregation: one wave per dst node, 2-pass softmax ----------
template<int H>  // H=4 -> HC=256 (lane owns 4 chans), H=1 -> HC=64 (lane owns 1)
__global__ __launch_bounds__(256) void gat_agg(const float* __restrict__ hL,
                                               const float* __restrict__ s,
                                               const float* __restrict__ d,
                                               const int* __restrict__ offs,
                                               const int* __restrict__ csr_src,
                                               const float* __restrict__ bias,
                                               float* __restrict__ out, int N) {
    const int HC = H * 64;
    int node = (blockIdx.x * blockDim.x + threadIdx.x) >> 6;
    int lane = threadIdx.x & 63;
    if (node >= N) return;
    int e0 = offs[node], e1 = offs[node + 1];

    float dd[H];
    #pragma unroll
    for (int h = 0; h < H; ++h) dd[h] = d[node * H + h];

    // phase 1: per-head max over incoming edges (lane-parallel over edges)
    float m[H];
    #pragma unroll
    for (int h = 0; h < H; ++h) m[h] = -INFINITY;
    for (int i = e0 + lane; i < e1; i += 64) {
        int src = csr_src[i];
        if (H == 4) {
            float4 sv = *(const float4*)&s[src * 4];
            float ev[4] = {sv.x, sv.y, sv.z, sv.w};
            #pragma unroll
            for (int h = 0; h < 4; ++h) m[h] = fmaxf(m[h], lrelu(ev[h] + dd[h]));
        } else {
            m[0] = fmaxf(m[0], lrelu(s[src] + dd[0]));
        }
    }
    #pragma unroll
    for (int h = 0; h < H; ++h)
        #pragma unroll
        for (int off = 32; off; off >>= 1) m[h] = fmaxf(m[h], __shfl_xor(m[h], off));

    // lane's head (static select -> no scratch)
    float mh = m[0], dh = dd[0];
    if (H == 4) {
        mh = (lane & 32) ? ((lane & 16) ? m[3] : m[2]) : ((lane & 16) ? m[1] : m[0]);
        dh = (lane & 32) ? ((lane & 16) ? dd[3] : dd[2]) : ((lane & 16) ? dd[1] : dd[0]);
    }
    const int hd = (H == 4) ? (lane >> 4) : 0;

    // phase 2: unnormalized weighted sum; lane covers its channels
    float acc0 = 0.f, acc1 = 0.f, acc2 = 0.f, acc3 = 0.f, den = 0.f;
    for (int i = e0; i < e1; ++i) {
        int src = csr_src[i];
        float sv = s[src * H + hd];
        float p = __expf(lrelu(sv + dh) - mh);
        den += p;
        if (H == 4) {
            float4 hv = *(const float4*)&hL[(size_t)src * HC + lane * 4];
            acc0 = fmaf(p, hv.x, acc0); acc1 = fmaf(p, hv.y, acc1);
            acc2 = fmaf(p, hv.z, acc2); acc3 = fmaf(p, hv.w, acc3);
        } else {
            float hv = hL[(size_t)src * 64 + lane];
            acc0 = fmaf(p, hv, acc0);
        }
    }
    float inv = 1.0f / (den + 1e-16f);
    if (H == 4) {
        float4 bv = *(const float4*)&bias[lane * 4];
        float4 o;
        o.x = elu_f(acc0 * inv + bv.x); o.y = elu_f(acc1 * inv + bv.y);
        o.z = elu_f(acc2 * inv + bv.z); o.w = elu_f(acc3 * inv + bv.w);
        *(float4*)&out[(size_t)node * HC + lane * 4] = o;
    } else {
        out[(size_t)node * 64 + lane] = elu_f(acc0 * inv + bias[lane]);
    }
}

// ---------- pooling ----------
__global__ void pool_init(float* gsum, unsigned* gmax, int* gcnt) {
    int t = blockIdx.x * blockDim.x + threadIdx.x;
    if (t < NG * 64) { gsum[t] = 0.f; gmax[t] = enc_f32(-INFINITY); }
    if (t < NG) gcnt[t] = 0;
}

__global__ void pool_reduce(const float* __restrict__ h3, const int* __restrict__ batch,
                            float* __restrict__ gsum, unsigned* __restrict__ gmax,
                            int* __restrict__ gcnt, int N, int per) {
    int w = (blockIdx.x * blockDim.x + threadIdx.x) >> 6;
    int lane = threadIdx.x & 63;
    int n0 = w * per;
    int n1 = min(N, n0 + per);
    float lsum = 0.f, lmax = -INFINITY;
    int cur = -1, cnt = 0;
    for (int n = n0; n < n1; ++n) {
        int g = batch[n];
        if (g != cur) {
            if (cur >= 0) {
                atomicAdd(&gsum[cur * 64 + lane], lsum);
                atomicMax(&gmax[cur * 64 + lane], enc_f32(lmax));
                if (lane == 0) atomicAdd(&gcnt[cur], cnt);
            }
            cur = g; lsum = 0.f; lmax = -INFINITY; cnt = 0;
        }
        float v = h3[(size_t)n * 64 + lane];
        lsum += v; lmax = fmaxf(lmax, v); cnt++;
    }
    if (cur >= 0) {
        atomicAdd(&gsum[cur * 64 + lane], lsum);
        atomicMax(&gmax[cur * 64 + lane], enc_f32(lmax));
        if (lane == 0) atomicAdd(&gcnt[cur], cnt);
    }
}

// ---------- classifier: one block per graph ----------
__global__ __launch_bounds__(128) void classifier(const float* __restrict__ gsum,
                                                  const unsigned* __restrict__ gmax,
                                                  const int* __restrict__ gcnt,
                                                  const float* __restrict__ Wc1,
                                                  const float* __restrict__ bc1,
                                                  const float* __restrict__ Wc2,
                                                  const float* __restrict__ bc2,
                                                  float* __restrict__ out) {
    __shared__ float gv[128];
    __shared__ float z1[64];
    int g = blockIdx.x, t = threadIdx.x;
    int cnt = gcnt[g];
    if (t < 64) {
        gv[t] = gsum[g * 64 + t] / fmaxf((float)cnt, 1.f);
    } else {
        float mx = dec_f32(gmax[g * 64 + (t - 64)]);
        gv[t] = (cnt > 0) ? mx : 0.f;
    }
    __syncthreads();
    if (t < 64) {
        float a = bc1[t];
        for (int k = 0; k < 128; ++k) a = fmaf(Wc1[t * 128 + k], gv[k], a);
        z1[t] = a > 0.f ? a : 0.f;
    }
    __syncthreads();
    if (t < 10) {
        float a = bc2[t];
        for (int k = 0; k < 64; ++k) a = fmaf(Wc2[t * 64 + k], z1[k], a);
        out[g * 10 + t] = a;
    }
}

// ---------- launch ----------
extern "C" void kernel_launch(void* const* d_in, const int* in_sizes, int n_in,
                              void* d_out, int out_size, void* d_ws, size_t ws_size,
                              hipStream_t stream) {
    const float* x      = (const float*)d_in[0];
    const int*   ei     = (const int*)d_in[1];
    const int*   batch  = (const int*)d_in[2];
    const float* W_emb  = (const float*)d_in[3];
    const float* b_emb  = (const float*)d_in[4];
    const float* W1     = (const float*)d_in[5];
    const float* as1    = (const float*)d_in[6];
    const float* ad1    = (const float*)d_in[7];
    const float* b1     = (const float*)d_in[8];
    const float* W2     = (const float*)d_in[9];
    const float* as2    = (const float*)d_in[10];
    const float* ad2    = (const float*)d_in[11];
    const float* b2     = (const float*)d_in[12];
    const float* W3     = (const float*)d_in[13];
    const float* as3    = (const float*)d_in[14];
    const float* ad3    = (const float*)d_in[15];
    const float* b3     = (const float*)d_in[16];
    const float* Wc1    = (const float*)d_in[17];
    const float* bc1    = (const float*)d_in[18];
    const float* Wc2    = (const float*)d_in[19];
    const float* bc2    = (const float*)d_in[20];

    const int N = in_sizes[0] / F_IN;   // 50000
    const int E = in_sizes[1] / 2;      // 800000
    const int ET = E + N;               // with self-loops

    // workspace carve-up (256B aligned)
    size_t off = 0;
    auto alloc = [&](size_t bytes) -> void* {
        void* p = (char*)d_ws + off;
        off += (bytes + 255) & ~(size_t)255;
        return p;
    };
    float*    A       = (float*)alloc((size_t)N * 64 * 4);    // h0 / agg3 out
    float*    B       = (float*)alloc((size_t)N * 256 * 4);   // gemm outputs
    float*    C       = (float*)alloc((size_t)N * 256 * 4);   // agg outputs
    float*    S       = (float*)alloc((size_t)N * 4 * 4);
    float*    D       = (float*)alloc((size_t)N * 4 * 4);
    int*      offs    = (int*)alloc((size_t)(N + 1) * 4);
    int*      cnt     = (int*)alloc((size_t)N * 4);           // also cursor
    int*      bsum    = (int*)alloc(64 * 4);
    int*      csr_src = (int*)alloc((size_t)ET * 4);
    float*    gsum    = (float*)alloc(NG * 64 * 4);
    unsigned* gmax    = (unsigned*)alloc(NG * 64 * 4);
    int*      gcnt    = (int*)alloc(NG * 4);
    (void)ws_size; (void)n_in; (void)out_size;

    const int SCB = (N + 1023) / 1024;

    // CSR build
    hipMemsetAsync(cnt, 0, (size_t)N * 4, stream);
    hist_kernel<<<(ET + 255) / 256, 256, 0, stream>>>(ei, cnt, E, N);
    scan1_kernel<<<SCB, 256, 0, stream>>>(cnt, offs, bsum, N);
    scan2_kernel<<<1, 64, 0, stream>>>(bsum, offs, SCB, N);
    scan3_kernel<<<SCB, 256, 0, stream>>>(offs, bsum, N);
    hipMemsetAsync(cnt, 0, (size_t)N * 4, stream);
    scatter_kernel<<<(ET + 255) / 256, 256, 0, stream>>>(ei, offs, cnt, csr_src, E, N);

    const int NWV = (N * 64 + 255) / 256;  // one wave per node kernels
    dim3 gN64((N + 63) / 64, 1);
    dim3 gN256((N + 63) / 64, 4);

    // embedding
    gemm_f32<128><<<gN64, 256, 0, stream>>>(x, W_emb, A, N, 64, b_emb);
    // GAT layer 1
    gemm_f32<64><<<gN256, 256, 0, stream>>>(A, W1, B, N, 256, nullptr);
    attn_sd<4><<<NWV, 256, 0, stream>>>(B, as1, ad1, S, D, N);
    gat_agg<4><<<NWV, 256, 0, stream>>>(B, S, D, offs, csr_src, b1, C, N);
    // GAT layer 2
    gemm_f32<256><<<gN256, 256, 0, stream>>>(C, W2, B, N, 256, nullptr);
    attn_sd<4><<<NWV, 256, 0, stream>>>(B, as2, ad2, S, D, N);
    gat_agg<4><<<NWV, 256, 0, stream>>>(B, S, D, offs, csr_src, b2, C, N);
    // GAT layer 3 (1 head)
    gemm_f32<256><<<gN64, 256, 0, stream>>>(C, W3, B, N, 64, nullptr);
    attn_sd<1><<<NWV, 256, 0, stream>>>(B, as3, ad3, S, D, N);
    gat_agg<1><<<NWV, 256, 0, stream>>>(B, S, D, offs, csr_src, b3, A, N);

    // pooling + classifier
    pool_init<<<16, 256, 0, stream>>>(gsum, gmax, gcnt);
    int per = (N + 255) / 256;  // 256 waves
    pool_reduce<<<64, 256, 0, stream>>>(A, batch, gsum, gmax, gcnt, N, per);
    classifier<<<NG, 128, 0, stream>>>(gsum, gmax, gcnt, Wc1, bc1, Wc2, bc2, (float*)d_out);
}

// Round 2
// 773.244 us; speedup vs baseline: 1.1552x; 1.1552x over previous
//
#include <hip/hip_runtime.h>
#include <math.h>

#define NG 64          // graphs
#define F_IN 128
#define NEG_SLOPE 0.2f

// ---------- helpers ----------
static __device__ __forceinline__ float elu_f(float x) { return x > 0.f ? x : expm1f(x); }
static __device__ __forceinline__ float lrelu(float x) { return x > 0.f ? x : NEG_SLOPE * x; }
static __device__ __forceinline__ unsigned enc_f32(float x) {
    unsigned u = __float_as_uint(x);
    return (u & 0x80000000u) ? ~u : (u | 0x80000000u);
}
static __device__ __forceinline__ float dec_f32(unsigned u) {
    unsigned b = (u & 0x80000000u) ? (u & 0x7fffffffu) : ~u;
    return __uint_as_float(b);
}

// ---------- CSR build ----------
__global__ void hist_kernel(const int* __restrict__ ei, int* __restrict__ cnt, int E, int N) {
    int e = blockIdx.x * blockDim.x + threadIdx.x;
    int ET = E + N;
    if (e >= ET) return;
    int dst = (e < E) ? ei[E + e] : (e - E);   // self-loops appended
    atomicAdd(&cnt[dst], 1);
}

__global__ void scan1_kernel(const int* __restrict__ cnt, int* __restrict__ excl,
                             int* __restrict__ bsum, int n) {
    __shared__ int sm[256];
    int t = threadIdx.x;
    int base = blockIdx.x * 1024 + t * 4;
    int v[4];
    #pragma unroll
    for (int u = 0; u < 4; ++u) { int idx = base + u; v[u] = (idx < n) ? cnt[idx] : 0; }
    int tsum = v[0] + v[1] + v[2] + v[3];
    sm[t] = tsum;
    __syncthreads();
    for (int off = 1; off < 256; off <<= 1) {
        int y = (t >= off) ? sm[t - off] : 0;
        __syncthreads();
        sm[t] += y;
        __syncthreads();
    }
    int run = sm[t] - tsum;  // exclusive base for this thread
    #pragma unroll
    for (int u = 0; u < 4; ++u) {
        int idx = base + u;
        if (idx < n) excl[idx] = run;
        run += v[u];
    }
    if (t == 255) bsum[blockIdx.x] = sm[255];
}

__global__ void scan2_kernel(int* __restrict__ bsum, int* __restrict__ offs, int nb, int n) {
    if (blockIdx.x == 0 && threadIdx.x == 0) {
        int run = 0;
        for (int b = 0; b < nb; ++b) { int t = bsum[b]; bsum[b] = run; run += t; }
        offs[n] = run;  // grand total = E + N
    }
}

__global__ void scan3_kernel(int* __restrict__ offs, const int* __restrict__ bsum, int n) {
    int base = blockIdx.x * 1024 + threadIdx.x * 4;
    int add = bsum[blockIdx.x];
    #pragma unroll
    for (int u = 0; u < 4; ++u) { int idx = base + u; if (idx < n) offs[idx] += add; }
}

__global__ void scatter_kernel(const int* __restrict__ ei, const int* __restrict__ offs,
                               int* __restrict__ cursor, int* __restrict__ csr_src, int E, int N) {
    int e = blockIdx.x * blockDim.x + threadIdx.x;
    int ET = E + N;
    if (e >= ET) return;
    int src, dst;
    if (e < E) { src = ei[e]; dst = ei[E + e]; }
    else       { src = e - E; dst = e - E; }
    int pos = offs[dst] + atomicAdd(&cursor[dst], 1);
    csr_src[pos] = src;
}

// ---------- f32 tiled GEMM with fused attention-scalar epilogue ----------
// Out[n][m] = dot(A[n][:K], W[m][:K]) + bias[m]
// If asrc != null: S[n*H+head] = dot(Out_row_headslice, asrc[head]), same for D.
// Each block owns (64 nodes) x (64 cols = one head slice) -> plain stores.
template<int K>
__global__ __launch_bounds__(256) void gemm_f32(const float* __restrict__ A,
                                                const float* __restrict__ W,
                                                float* __restrict__ Out,
                                                int N, int M, const float* __restrict__ bias,
                                                const float* __restrict__ asrc,
                                                const float* __restrict__ adst,
                                                float* __restrict__ S, float* __restrict__ D,
                                                int H) {
    __shared__ __align__(16) float As[32][68];
    __shared__ __align__(16) float Bs[32][68];
    const int t = threadIdx.x;
    const int n0 = blockIdx.x * 64;
    const int m0 = blockIdx.y * 64;
    const int i = t >> 4, j = t & 15;
    float acc[4][4] = {};
    for (int kc = 0; kc < K; kc += 32) {
        __syncthreads();
        for (int l = t; l < 512; l += 256) {
            int row = l >> 3, q = l & 7;
            int gr = n0 + row;
            float4 av = make_float4(0.f, 0.f, 0.f, 0.f);
            if (gr < N) av = *(const float4*)&A[(size_t)gr * K + kc + 4 * q];
            As[4 * q + 0][row] = av.x; As[4 * q + 1][row] = av.y;
            As[4 * q + 2][row] = av.z; As[4 * q + 3][row] = av.w;
            float4 bv = *(const float4*)&W[(size_t)(m0 + row) * K + kc + 4 * q];
            Bs[4 * q + 0][row] = bv.x; Bs[4 * q + 1][row] = bv.y;
            Bs[4 * q + 2][row] = bv.z; Bs[4 * q + 3][row] = bv.w;
        }
        __syncthreads();
        #pragma unroll
        for (int k = 0; k < 32; ++k) {
            float4 av = *(const float4*)&As[k][4 * i];
            float4 bv = *(const float4*)&Bs[k][4 * j];
            float a[4] = {av.x, av.y, av.z, av.w};
            float b[4] = {bv.x, bv.y, bv.z, bv.w};
            #pragma unroll
            for (int r = 0; r < 4; ++r)
                #pragma unroll
                for (int c = 0; c < 4; ++c) acc[r][c] = fmaf(a[r], b[c], acc[r][c]);
        }
    }
    float4 bias4 = make_float4(0.f, 0.f, 0.f, 0.f);
    if (bias) bias4 = *(const float4*)&bias[m0 + 4 * j];
    #pragma unroll
    for (int r = 0; r < 4; ++r) {
        int gr = n0 + 4 * i + r;
        if (gr < N) {
            float4 o;
            o.x = acc[r][0] + bias4.x; o.y = acc[r][1] + bias4.y;
            o.z = acc[r][2] + bias4.z; o.w = acc[r][3] + bias4.w;
            *(float4*)&Out[(size_t)gr * M + m0 + 4 * j] = o;
        }
    }
    // fused attention scalars (per head slice = this block's 64 columns)
    if (asrc) {
        const int head = blockIdx.y;
        float4 av = *(const float4*)&asrc[head * 64 + 4 * j];
        float4 dv = *(const float4*)&adst[head * 64 + 4 * j];
        #pragma unroll
        for (int r = 0; r < 4; ++r) {
            float sp = acc[r][0] * av.x + acc[r][1] * av.y + acc[r][2] * av.z + acc[r][3] * av.w;
            float dp = acc[r][0] * dv.x + acc[r][1] * dv.y + acc[r][2] * dv.z + acc[r][3] * dv.w;
            #pragma unroll
            for (int off = 1; off < 16; off <<= 1) {
                sp += __shfl_xor(sp, off);
                dp += __shfl_xor(dp, off);
            }
            if (j == 0) {
                int node = n0 + 4 * i + r;
                if (node < N) { S[node * H + head] = sp; D[node * H + head] = dp; }
            }
        }
    }
}

// ---------- GAT aggregation: one wave per dst node, 2-pass softmax ----------
template<int H>  // H=4 -> HC=256 (lane owns 4 chans), H=1 -> HC=64 (lane owns 1)
__global__ __launch_bounds__(256) void gat_agg(const float* __restrict__ hL,
                                               const float* __restrict__ s,
                                               const float* __restrict__ d,
                                               const int* __restrict__ offs,
                                               const int* __restrict__ csr_src,
                                               const float* __restrict__ bias,
                                               float* __restrict__ out, int N) {
    const int HC = H * 64;
    int node = (blockIdx.x * blockDim.x + threadIdx.x) >> 6;
    int lane = threadIdx.x & 63;
    if (node >= N) return;
    int e0 = offs[node], e1 = offs[node + 1];

    float dd[H];
    #pragma unroll
    for (int h = 0; h < H; ++h) dd[h] = d[node * H + h];

    // phase 1: per-head max over incoming edges (lane-parallel over edges)
    float m[H];
    #pragma unroll
    for (int h = 0; h < H; ++h) m[h] = -INFINITY;
    for (int i = e0 + lane; i < e1; i += 64) {
        int src = csr_src[i];
        if (H == 4) {
            float4 sv = *(const float4*)&s[src * 4];
            float ev[4] = {sv.x, sv.y, sv.z, sv.w};
            #pragma unroll
            for (int h = 0; h < 4; ++h) m[h] = fmaxf(m[h], lrelu(ev[h] + dd[h]));
        } else {
            m[0] = fmaxf(m[0], lrelu(s[src] + dd[0]));
        }
    }
    #pragma unroll
    for (int h = 0; h < H; ++h)
        #pragma unroll
        for (int off = 32; off; off >>= 1) m[h] = fmaxf(m[h], __shfl_xor(m[h], off));

    // lane's head (static select -> no scratch)
    float mh = m[0], dh = dd[0];
    if (H == 4) {
        mh = (lane & 32) ? ((lane & 16) ? m[3] : m[2]) : ((lane & 16) ? m[1] : m[0]);
        dh = (lane & 32) ? ((lane & 16) ? dd[3] : dd[2]) : ((lane & 16) ? dd[1] : dd[0]);
    }
    const int hd = (H == 4) ? (lane >> 4) : 0;

    // phase 2: unnormalized weighted sum, 4-way unrolled for memory-level parallelism
    float acc0 = 0.f, acc1 = 0.f, acc2 = 0.f, acc3 = 0.f, den = 0.f;
    int i = e0;
    for (; i + 4 <= e1; i += 4) {
        int sa = csr_src[i + 0];
        int sb = csr_src[i + 1];
        int sc = csr_src[i + 2];
        int sd_ = csr_src[i + 3];
        float pa = __expf(lrelu(s[sa * H + hd] + dh) - mh);
        float pb = __expf(lrelu(s[sb * H + hd] + dh) - mh);
        float pc = __expf(lrelu(s[sc * H + hd] + dh) - mh);
        float pd = __expf(lrelu(s[sd_ * H + hd] + dh) - mh);
        den += (pa + pb) + (pc + pd);
        if (H == 4) {
            float4 ha = *(const float4*)&hL[(size_t)sa * HC + lane * 4];
            float4 hb = *(const float4*)&hL[(size_t)sb * HC + lane * 4];
            float4 hc = *(const float4*)&hL[(size_t)sc * HC + lane * 4];
            float4 hdv = *(const float4*)&hL[(size_t)sd_ * HC + lane * 4];
            acc0 = fmaf(pa, ha.x, acc0); acc1 = fmaf(pa, ha.y, acc1);
            acc2 = fmaf(pa, ha.z, acc2); acc3 = fmaf(pa, ha.w, acc3);
            acc0 = fmaf(pb, hb.x, acc0); acc1 = fmaf(pb, hb.y, acc1);
            acc2 = fmaf(pb, hb.z, acc2); acc3 = fmaf(pb, hb.w, acc3);
            acc0 = fmaf(pc, hc.x, acc0); acc1 = fmaf(pc, hc.y, acc1);
            acc2 = fmaf(pc, hc.z, acc2); acc3 = fmaf(pc, hc.w, acc3);
            acc0 = fmaf(pd, hdv.x, acc0); acc1 = fmaf(pd, hdv.y, acc1);
            acc2 = fmaf(pd, hdv.z, acc2); acc3 = fmaf(pd, hdv.w, acc3);
        } else {
            float ha = hL[(size_t)sa * 64 + lane];
            float hb = hL[(size_t)sb * 64 + lane];
            float hc = hL[(size_t)sc * 64 + lane];
            float hdv = hL[(size_t)sd_ * 64 + lane];
            acc0 = fmaf(pa, ha, acc0);
            acc0 = fmaf(pb, hb, acc0);
            acc0 = fmaf(pc, hc, acc0);
            acc0 = fmaf(pd, hdv, acc0);
        }
    }
    for (; i < e1; ++i) {
        int src = csr_src[i];
        float p = __expf(lrelu(s[src * H + hd] + dh) - mh);
        den += p;
        if (H == 4) {
            float4 hv = *(const float4*)&hL[(size_t)src * HC + lane * 4];
            acc0 = fmaf(p, hv.x, acc0); acc1 = fmaf(p, hv.y, acc1);
            acc2 = fmaf(p, hv.z, acc2); acc3 = fmaf(p, hv.w, acc3);
        } else {
            float hv = hL[(size_t)src * 64 + lane];
            acc0 = fmaf(p, hv, acc0);
        }
    }
    float inv = 1.0f / (den + 1e-16f);
    if (H == 4) {
        float4 bv = *(const float4*)&bias[lane * 4];
        float4 o;
        o.x = elu_f(acc0 * inv + bv.x); o.y = elu_f(acc1 * inv + bv.y);
        o.z = elu_f(acc2 * inv + bv.z); o.w = elu_f(acc3 * inv + bv.w);
        *(float4*)&out[(size_t)node * HC + lane * 4] = o;
    } else {
        out[(size_t)node * 64 + lane] = elu_f(acc0 * inv + bias[lane]);
    }
}

// ---------- pooling ----------
__global__ void pool_init(float* gsum, unsigned* gmax, int* gcnt) {
    int t = blockIdx.x * blockDim.x + threadIdx.x;
    if (t < NG * 64) { gsum[t] = 0.f; gmax[t] = enc_f32(-INFINITY); }
    if (t < NG) gcnt[t] = 0;
}

__global__ void pool_reduce(const float* __restrict__ h3, const int* __restrict__ batch,
                            float* __restrict__ gsum, unsigned* __restrict__ gmax,
                            int* __restrict__ gcnt, int N, int per) {
    int w = (blockIdx.x * blockDim.x + threadIdx.x) >> 6;
    int lane = threadIdx.x & 63;
    int n0 = w * per;
    int n1 = min(N, n0 + per);
    float lsum = 0.f, lmax = -INFINITY;
    int cur = -1, cnt = 0;
    for (int n = n0; n < n1; ++n) {
        int g = batch[n];
        if (g != cur) {
            if (cur >= 0) {
                atomicAdd(&gsum[cur * 64 + lane], lsum);
                atomicMax(&gmax[cur * 64 + lane], enc_f32(lmax));
                if (lane == 0) atomicAdd(&gcnt[cur], cnt);
            }
            cur = g; lsum = 0.f; lmax = -INFINITY; cnt = 0;
        }
        float v = h3[(size_t)n * 64 + lane];
        lsum += v; lmax = fmaxf(lmax, v); cnt++;
    }
    if (cur >= 0) {
        atomicAdd(&gsum[cur * 64 + lane], lsum);
        atomicMax(&gmax[cur * 64 + lane], enc_f32(lmax));
        if (lane == 0) atomicAdd(&gcnt[cur], cnt);
    }
}

// ---------- classifier: one block per graph ----------
__global__ __launch_bounds__(128) void classifier(const float* __restrict__ gsum,
                                                  const unsigned* __restrict__ gmax,
                                                  const int* __restrict__ gcnt,
                                                  const float* __restrict__ Wc1,
                                                  const float* __restrict__ bc1,
                                                  const float* __restrict__ Wc2,
                                                  const float* __restrict__ bc2,
                                                  float* __restrict__ out) {
    __shared__ float gv[128];
    __shared__ float z1[64];
    int g = blockIdx.x, t = threadIdx.x;
    int cnt = gcnt[g];
    if (t < 64) {
        gv[t] = gsum[g * 64 + t] / fmaxf((float)cnt, 1.f);
    } else {
        float mx = dec_f32(gmax[g * 64 + (t - 64)]);
        gv[t] = (cnt > 0) ? mx : 0.f;
    }
    __syncthreads();
    if (t < 64) {
        float a = bc1[t];
        for (int k = 0; k < 128; ++k) a = fmaf(Wc1[t * 128 + k], gv[k], a);
        z1[t] = a > 0.f ? a : 0.f;
    }
    __syncthreads();
    if (t < 10) {
        float a = bc2[t];
        for (int k = 0; k < 64; ++k) a = fmaf(Wc2[t * 64 + k], z1[k], a);
        out[g * 10 + t] = a;
    }
}

// ---------- launch ----------
extern "C" void kernel_launch(void* const* d_in, const int* in_sizes, int n_in,
                              void* d_out, int out_size, void* d_ws, size_t ws_size,
                              hipStream_t stream) {
    const float* x      = (const float*)d_in[0];
    const int*   ei     = (const int*)d_in[1];
    const int*   batch  = (const int*)d_in[2];
    const float* W_emb  = (const float*)d_in[3];
    const float* b_emb  = (const float*)d_in[4];
    const float* W1     = (const float*)d_in[5];
    const float* as1    = (const float*)d_in[6];
    const float* ad1    = (const float*)d_in[7];
    const float* b1     = (const float*)d_in[8];
    const float* W2     = (const float*)d_in[9];
    const float* as2    = (const float*)d_in[10];
    const float* ad2    = (const float*)d_in[11];
    const float* b2     = (const float*)d_in[12];
    const float* W3     = (const float*)d_in[13];
    const float* as3    = (const float*)d_in[14];
    const float* ad3    = (const float*)d_in[15];
    const float* b3     = (const float*)d_in[16];
    const float* Wc1    = (const float*)d_in[17];
    const float* bc1    = (const float*)d_in[18];
    const float* Wc2    = (const float*)d_in[19];
    const float* bc2    = (const float*)d_in[20];

    const int N = in_sizes[0] / F_IN;   // 50000
    const int E = in_sizes[1] / 2;      // 800000
    const int ET = E + N;               // with self-loops

    // workspace carve-up (256B aligned)
    size_t off = 0;
    auto alloc = [&](size_t bytes) -> void* {
        void* p = (char*)d_ws + off;
        off += (bytes + 255) & ~(size_t)255;
        return p;
    };
    float*    A       = (float*)alloc((size_t)N * 64 * 4);    // h0 / agg3 out
    float*    B       = (float*)alloc((size_t)N * 256 * 4);   // gemm outputs
    float*    C       = (float*)alloc((size_t)N * 256 * 4);   // agg outputs
    float*    S       = (float*)alloc((size_t)N * 4 * 4);
    float*    D       = (float*)alloc((size_t)N * 4 * 4);
    int*      offs    = (int*)alloc((size_t)(N + 1) * 4);
    int*      cnt     = (int*)alloc((size_t)N * 4);           // also cursor
    int*      bsum    = (int*)alloc(64 * 4);
    int*      csr_src = (int*)alloc((size_t)ET * 4);
    float*    gsum    = (float*)alloc(NG * 64 * 4);
    unsigned* gmax    = (unsigned*)alloc(NG * 64 * 4);
    int*      gcnt    = (int*)alloc(NG * 4);
    (void)ws_size; (void)n_in; (void)out_size;

    const int SCB = (N + 1023) / 1024;

    // CSR build
    hipMemsetAsync(cnt, 0, (size_t)N * 4, stream);
    hist_kernel<<<(ET + 255) / 256, 256, 0, stream>>>(ei, cnt, E, N);
    scan1_kernel<<<SCB, 256, 0, stream>>>(cnt, offs, bsum, N);
    scan2_kernel<<<1, 64, 0, stream>>>(bsum, offs, SCB, N);
    scan3_kernel<<<SCB, 256, 0, stream>>>(offs, bsum, N);
    hipMemsetAsync(cnt, 0, (size_t)N * 4, stream);
    scatter_kernel<<<(ET + 255) / 256, 256, 0, stream>>>(ei, offs, cnt, csr_src, E, N);

    const int NWV = (N * 64 + 255) / 256;  // one wave per node kernels
    dim3 gN64((N + 63) / 64, 1);
    dim3 gN256((N + 63) / 64, 4);

    // embedding (no attn epilogue)
    gemm_f32<128><<<gN64, 256, 0, stream>>>(x, W_emb, A, N, 64, b_emb,
                                            nullptr, nullptr, nullptr, nullptr, 0);
    // GAT layer 1
    gemm_f32<64><<<gN256, 256, 0, stream>>>(A, W1, B, N, 256, nullptr,
                                            as1, ad1, S, D, 4);
    gat_agg<4><<<NWV, 256, 0, stream>>>(B, S, D, offs, csr_src, b1, C, N);
    // GAT layer 2
    gemm_f32<256><<<gN256, 256, 0, stream>>>(C, W2, B, N, 256, nullptr,
                                             as2, ad2, S, D, 4);
    gat_agg<4><<<NWV, 256, 0, stream>>>(B, S, D, offs, csr_src, b2, C, N);
    // GAT layer 3 (1 head)
    gemm_f32<256><<<gN64, 256, 0, stream>>>(C, W3, B, N, 64, nullptr,
                                            as3, ad3, S, D, 1);
    gat_agg<1><<<NWV, 256, 0, stream>>>(B, S, D, offs, csr_src, b3, A, N);

    // pooling + classifier
    pool_init<<<16, 256, 0, stream>>>(gsum, gmax, gcnt);
    int per = (N + 255) / 256;  // 256 waves
    pool_reduce<<<64, 256, 0, stream>>>(A, batch, gsum, gmax, gcnt, N, per);
    classifier<<<NG, 128, 0, stream>>>(gsum, gmax, gcnt, Wc1, bc1, Wc2, bc2, (float*)d_out);
}

// Round 3
// 767.563 us; speedup vs baseline: 1.1637x; 1.0074x over previous
//
#include <hip/hip_runtime.h>
#include <math.h>

#define NG 64          // graphs
#define F_IN 128
#define NEG_SLOPE 0.2f

// ---------- helpers ----------
static __device__ __forceinline__ float elu_f(float x) { return x > 0.f ? x : expm1f(x); }
static __device__ __forceinline__ float lrelu(float x) { return x > 0.f ? x : NEG_SLOPE * x; }
static __device__ __forceinline__ unsigned enc_f32(float x) {
    unsigned u = __float_as_uint(x);
    return (u & 0x80000000u) ? ~u : (u | 0x80000000u);
}
static __device__ __forceinline__ float dec_f32(unsigned u) {
    unsigned b = (u & 0x80000000u) ? (u & 0x7fffffffu) : ~u;
    return __uint_as_float(b);
}

// ---------- CSR build ----------
__global__ void hist_kernel(const int* __restrict__ ei, int* __restrict__ cnt, int E, int N) {
    int e = blockIdx.x * blockDim.x + threadIdx.x;
    int ET = E + N;
    if (e >= ET) return;
    int dst = (e < E) ? ei[E + e] : (e - E);   // self-loops appended
    atomicAdd(&cnt[dst], 1);
}

__global__ void scan1_kernel(const int* __restrict__ cnt, int* __restrict__ excl,
                             int* __restrict__ bsum, int n) {
    __shared__ int sm[256];
    int t = threadIdx.x;
    int base = blockIdx.x * 1024 + t * 4;
    int v[4];
    #pragma unroll
    for (int u = 0; u < 4; ++u) { int idx = base + u; v[u] = (idx < n) ? cnt[idx] : 0; }
    int tsum = v[0] + v[1] + v[2] + v[3];
    sm[t] = tsum;
    __syncthreads();
    for (int off = 1; off < 256; off <<= 1) {
        int y = (t >= off) ? sm[t - off] : 0;
        __syncthreads();
        sm[t] += y;
        __syncthreads();
    }
    int run = sm[t] - tsum;  // exclusive base for this thread
    #pragma unroll
    for (int u = 0; u < 4; ++u) {
        int idx = base + u;
        if (idx < n) excl[idx] = run;
        run += v[u];
    }
    if (t == 255) bsum[blockIdx.x] = sm[255];
}

__global__ void scan2_kernel(int* __restrict__ bsum, int* __restrict__ offs, int nb, int n) {
    if (blockIdx.x == 0 && threadIdx.x == 0) {
        int run = 0;
        for (int b = 0; b < nb; ++b) { int t = bsum[b]; bsum[b] = run; run += t; }
        offs[n] = run;  // grand total = E + N
    }
}

__global__ void scan3_kernel(int* __restrict__ offs, const int* __restrict__ bsum, int n) {
    int base = blockIdx.x * 1024 + threadIdx.x * 4;
    int add = bsum[blockIdx.x];
    #pragma unroll
    for (int u = 0; u < 4; ++u) { int idx = base + u; if (idx < n) offs[idx] += add; }
}

__global__ void scatter_kernel(const int* __restrict__ ei, const int* __restrict__ offs,
                               int* __restrict__ cursor, int* __restrict__ csr_src, int E, int N) {
    int e = blockIdx.x * blockDim.x + threadIdx.x;
    int ET = E + N;
    if (e >= ET) return;
    int src, dst;
    if (e < E) { src = ei[e]; dst = ei[E + e]; }
    else       { src = e - E; dst = e - E; }
    int pos = offs[dst] + atomicAdd(&cursor[dst], 1);
    csr_src[pos] = src;
}

// ---------- f32 tiled GEMM with fused attention-scalar epilogue ----------
template<int K>
__global__ __launch_bounds__(256) void gemm_f32(const float* __restrict__ A,
                                                const float* __restrict__ W,
                                                float* __restrict__ Out,
                                                int N, int M, const float* __restrict__ bias,
                                                const float* __restrict__ asrc,
                                                const float* __restrict__ adst,
                                                float* __restrict__ S, float* __restrict__ D,
                                                int H) {
    __shared__ __align__(16) float As[32][68];
    __shared__ __align__(16) float Bs[32][68];
    const int t = threadIdx.x;
    const int n0 = blockIdx.x * 64;
    const int m0 = blockIdx.y * 64;
    const int i = t >> 4, j = t & 15;
    float acc[4][4] = {};
    for (int kc = 0; kc < K; kc += 32) {
        __syncthreads();
        for (int l = t; l < 512; l += 256) {
            int row = l >> 3, q = l & 7;
            int gr = n0 + row;
            float4 av = make_float4(0.f, 0.f, 0.f, 0.f);
            if (gr < N) av = *(const float4*)&A[(size_t)gr * K + kc + 4 * q];
            As[4 * q + 0][row] = av.x; As[4 * q + 1][row] = av.y;
            As[4 * q + 2][row] = av.z; As[4 * q + 3][row] = av.w;
            float4 bv = *(const float4*)&W[(size_t)(m0 + row) * K + kc + 4 * q];
            Bs[4 * q + 0][row] = bv.x; Bs[4 * q + 1][row] = bv.y;
            Bs[4 * q + 2][row] = bv.z; Bs[4 * q + 3][row] = bv.w;
        }
        __syncthreads();
        #pragma unroll
        for (int k = 0; k < 32; ++k) {
            float4 av = *(const float4*)&As[k][4 * i];
            float4 bv = *(const float4*)&Bs[k][4 * j];
            float a[4] = {av.x, av.y, av.z, av.w};
            float b[4] = {bv.x, bv.y, bv.z, bv.w};
            #pragma unroll
            for (int r = 0; r < 4; ++r)
                #pragma unroll
                for (int c = 0; c < 4; ++c) acc[r][c] = fmaf(a[r], b[c], acc[r][c]);
        }
    }
    float4 bias4 = make_float4(0.f, 0.f, 0.f, 0.f);
    if (bias) bias4 = *(const float4*)&bias[m0 + 4 * j];
    #pragma unroll
    for (int r = 0; r < 4; ++r) {
        int gr = n0 + 4 * i + r;
        if (gr < N) {
            float4 o;
            o.x = acc[r][0] + bias4.x; o.y = acc[r][1] + bias4.y;
            o.z = acc[r][2] + bias4.z; o.w = acc[r][3] + bias4.w;
            *(float4*)&Out[(size_t)gr * M + m0 + 4 * j] = o;
        }
    }
    // fused attention scalars (per head slice = this block's 64 columns)
    if (asrc) {
        const int head = blockIdx.y;
        float4 av = *(const float4*)&asrc[head * 64 + 4 * j];
        float4 dv = *(const float4*)&adst[head * 64 + 4 * j];
        #pragma unroll
        for (int r = 0; r < 4; ++r) {
            float sp = acc[r][0] * av.x + acc[r][1] * av.y + acc[r][2] * av.z + acc[r][3] * av.w;
            float dp = acc[r][0] * dv.x + acc[r][1] * dv.y + acc[r][2] * dv.z + acc[r][3] * dv.w;
            #pragma unroll
            for (int off = 1; off < 16; off <<= 1) {
                sp += __shfl_xor(sp, off);
                dp += __shfl_xor(dp, off);
            }
            if (j == 0) {
                int node = n0 + 4 * i + r;
                if (node < N) { S[node * H + head] = sp; D[node * H + head] = dp; }
            }
        }
    }
}

// ---------- GAT aggregation: one wave per dst node, chunked online softmax ----------
// Per 64-edge chunk: lanes cooperatively stage (e=lrelu(s+d), src) into per-wave LDS,
// shuffle-reduce chunk max, online-rescale accumulators, then accumulate with
// 4 independent h-row gathers in flight (only global loads in the hot loop).
template<int H>  // H=4 -> HC=256 (lane owns 4 chans), H=1 -> HC=64 (lane owns 1)
__global__ __launch_bounds__(256, 8) void gat_agg(const float* __restrict__ hL,
                                                  const float* __restrict__ s,
                                                  const float* __restrict__ d,
                                                  const int* __restrict__ offs,
                                                  const int* __restrict__ csr_src,
                                                  const float* __restrict__ bias,
                                                  float* __restrict__ out, int N) {
    const int HC = H * 64;
    const int SW = (H == 4) ? 5 : 2;     // stash words per edge
    __shared__ float stash[4][64 * 5];   // per-wave slice; no cross-wave sharing -> no barrier
    int wv = threadIdx.x >> 6;
    int lane = threadIdx.x & 63;
    int node = (blockIdx.x * blockDim.x + threadIdx.x) >> 6;
    if (node >= N) return;
    float* st = stash[wv];
    int e0 = offs[node], e1 = offs[node + 1];

    float dd[H];
    #pragma unroll
    for (int h = 0; h < H; ++h) dd[h] = d[node * H + h];

    // lane's head for the accumulate phase
    const int hd = (H == 4) ? (lane >> 4) : 0;

    float mrun = -INFINITY;
    float acc0 = 0.f, acc1 = 0.f, acc2 = 0.f, acc3 = 0.f, den = 0.f;

    for (int base = e0; base < e1; base += 64) {
        int cnt = min(64, e1 - base);
        // --- stage chunk: e scores + src into LDS ---
        float ev[H];
        #pragma unroll
        for (int h = 0; h < H; ++h) ev[h] = -INFINITY;
        if (lane < cnt) {
            int src = csr_src[base + lane];
            if (H == 4) {
                float4 sv = *(const float4*)&s[src * 4];
                ev[0] = lrelu(sv.x + dd[0]); ev[1] = lrelu(sv.y + dd[1]);
                ev[2] = lrelu(sv.z + dd[2]); ev[3] = lrelu(sv.w + dd[3]);
                st[lane * 5 + 0] = ev[0]; st[lane * 5 + 1] = ev[1];
                st[lane * 5 + 2] = ev[2]; st[lane * 5 + 3] = ev[3];
                st[lane * 5 + 4] = __int_as_float(src);
            } else {
                ev[0] = lrelu(s[src] + dd[0]);
                st[lane * 2 + 0] = ev[0];
                st[lane * 2 + 1] = __int_as_float(src);
            }
        }
        // --- chunk max per head (over all 64 lanes, inactive = -INF) ---
        float mc[H];
        #pragma unroll
        for (int h = 0; h < H; ++h) {
            float m = ev[h];
            #pragma unroll
            for (int off = 32; off; off >>= 1) m = fmaxf(m, __shfl_xor(m, off));
            mc[h] = m;
        }
        float mch = mc[0];
        if (H == 4)
            mch = (lane & 32) ? ((lane & 16) ? mc[3] : mc[2]) : ((lane & 16) ? mc[1] : mc[0]);
        float mnew = fmaxf(mrun, mch);
        float scale = __expf(mrun - mnew);   // first chunk: exp(-inf)=0, acc/den already 0
        acc0 *= scale; acc1 *= scale; acc2 *= scale; acc3 *= scale; den *= scale;
        mrun = mnew;

        // --- accumulate chunk: LDS-fed, 4 gathers in flight ---
        int k = 0;
        for (; k + 4 <= cnt; k += 4) {
            float ea = st[(k + 0) * SW + hd];
            float eb = st[(k + 1) * SW + hd];
            float ec = st[(k + 2) * SW + hd];
            float ed = st[(k + 3) * SW + hd];
            int sa = __float_as_int(st[(k + 0) * SW + SW - 1]);
            int sb = __float_as_int(st[(k + 1) * SW + SW - 1]);
            int sc = __float_as_int(st[(k + 2) * SW + SW - 1]);
            int sd_ = __float_as_int(st[(k + 3) * SW + SW - 1]);
            float pa = __expf(ea - mrun);
            float pb = __expf(eb - mrun);
            float pc = __expf(ec - mrun);
            float pd = __expf(ed - mrun);
            den += (pa + pb) + (pc + pd);
            if (H == 4) {
                float4 ha = *(const float4*)&hL[(size_t)sa * 256 + lane * 4];
                float4 hb = *(const float4*)&hL[(size_t)sb * 256 + lane * 4];
                float4 hc = *(const float4*)&hL[(size_t)sc * 256 + lane * 4];
                float4 hdv = *(const float4*)&hL[(size_t)sd_ * 256 + lane * 4];
                acc0 = fmaf(pa, ha.x, acc0); acc1 = fmaf(pa, ha.y, acc1);
                acc2 = fmaf(pa, ha.z, acc2); acc3 = fmaf(pa, ha.w, acc3);
                acc0 = fmaf(pb, hb.x, acc0); acc1 = fmaf(pb, hb.y, acc1);
                acc2 = fmaf(pb, hb.z, acc2); acc3 = fmaf(pb, hb.w, acc3);
                acc0 = fmaf(pc, hc.x, acc0); acc1 = fmaf(pc, hc.y, acc1);
                acc2 = fmaf(pc, hc.z, acc2); acc3 = fmaf(pc, hc.w, acc3);
                acc0 = fmaf(pd, hdv.x, acc0); acc1 = fmaf(pd, hdv.y, acc1);
                acc2 = fmaf(pd, hdv.z, acc2); acc3 = fmaf(pd, hdv.w, acc3);
            } else {
                float ha = hL[(size_t)sa * 64 + lane];
                float hb = hL[(size_t)sb * 64 + lane];
                float hc = hL[(size_t)sc * 64 + lane];
                float hdv = hL[(size_t)sd_ * 64 + lane];
                acc0 = fmaf(pa, ha, acc0);
                acc0 = fmaf(pb, hb, acc0);
                acc0 = fmaf(pc, hc, acc0);
                acc0 = fmaf(pd, hdv, acc0);
            }
        }
        for (; k < cnt; ++k) {
            float e = st[k * SW + hd];
            int src = __float_as_int(st[k * SW + SW - 1]);
            float p = __expf(e - mrun);
            den += p;
            if (H == 4) {
                float4 hv = *(const float4*)&hL[(size_t)src * 256 + lane * 4];
                acc0 = fmaf(p, hv.x, acc0); acc1 = fmaf(p, hv.y, acc1);
                acc2 = fmaf(p, hv.z, acc2); acc3 = fmaf(p, hv.w, acc3);
            } else {
                float hv = hL[(size_t)src * 64 + lane];
                acc0 = fmaf(p, hv, acc0);
            }
        }
    }

    float inv = 1.0f / (den + 1e-16f);
    if (H == 4) {
        float4 bv = *(const float4*)&bias[lane * 4];
        float4 o;
        o.x = elu_f(acc0 * inv + bv.x); o.y = elu_f(acc1 * inv + bv.y);
        o.z = elu_f(acc2 * inv + bv.z); o.w = elu_f(acc3 * inv + bv.w);
        *(float4*)&out[(size_t)node * 256 + lane * 4] = o;
    } else {
        out[(size_t)node * 64 + lane] = elu_f(acc0 * inv + bias[lane]);
    }
}

// ---------- pooling ----------
__global__ void pool_init(float* gsum, unsigned* gmax, int* gcnt) {
    int t = blockIdx.x * blockDim.x + threadIdx.x;
    if (t < NG * 64) { gsum[t] = 0.f; gmax[t] = enc_f32(-INFINITY); }
    if (t < NG) gcnt[t] = 0;
}

__global__ void pool_reduce(const float* __restrict__ h3, const int* __restrict__ batch,
                            float* __restrict__ gsum, unsigned* __restrict__ gmax,
                            int* __restrict__ gcnt, int N, int per) {
    int w = (blockIdx.x * blockDim.x + threadIdx.x) >> 6;
    int lane = threadIdx.x & 63;
    int n0 = w * per;
    int n1 = min(N, n0 + per);
    float lsum = 0.f, lmax = -INFINITY;
    int cur = -1, cnt = 0;
    for (int n = n0; n < n1; ++n) {
        int g = batch[n];
        if (g != cur) {
            if (cur >= 0) {
                atomicAdd(&gsum[cur * 64 + lane], lsum);
                atomicMax(&gmax[cur * 64 + lane], enc_f32(lmax));
                if (lane == 0) atomicAdd(&gcnt[cur], cnt);
            }
            cur = g; lsum = 0.f; lmax = -INFINITY; cnt = 0;
        }
        float v = h3[(size_t)n * 64 + lane];
        lsum += v; lmax = fmaxf(lmax, v); cnt++;
    }
    if (cur >= 0) {
        atomicAdd(&gsum[cur * 64 + lane], lsum);
        atomicMax(&gmax[cur * 64 + lane], enc_f32(lmax));
        if (lane == 0) atomicAdd(&gcnt[cur], cnt);
    }
}

// ---------- classifier: one block per graph ----------
__global__ __launch_bounds__(128) void classifier(const float* __restrict__ gsum,
                                                  const unsigned* __restrict__ gmax,
                                                  const int* __restrict__ gcnt,
                                                  const float* __restrict__ Wc1,
                                                  const float* __restrict__ bc1,
                                                  const float* __restrict__ Wc2,
                                                  const float* __restrict__ bc2,
                                                  float* __restrict__ out) {
    __shared__ float gv[128];
    __shared__ float z1[64];
    int g = blockIdx.x, t = threadIdx.x;
    int cnt = gcnt[g];
    if (t < 64) {
        gv[t] = gsum[g * 64 + t] / fmaxf((float)cnt, 1.f);
    } else {
        float mx = dec_f32(gmax[g * 64 + (t - 64)]);
        gv[t] = (cnt > 0) ? mx : 0.f;
    }
    __syncthreads();
    if (t < 64) {
        float a = bc1[t];
        for (int k = 0; k < 128; ++k) a = fmaf(Wc1[t * 128 + k], gv[k], a);
        z1[t] = a > 0.f ? a : 0.f;
    }
    __syncthreads();
    if (t < 10) {
        float a = bc2[t];
        for (int k = 0; k < 64; ++k) a = fmaf(Wc2[t * 64 + k], z1[k], a);
        out[g * 10 + t] = a;
    }
}

// ---------- launch ----------
extern "C" void kernel_launch(void* const* d_in, const int* in_sizes, int n_in,
                              void* d_out, int out_size, void* d_ws, size_t ws_size,
                              hipStream_t stream) {
    const float* x      = (const float*)d_in[0];
    const int*   ei     = (const int*)d_in[1];
    const int*   batch  = (const int*)d_in[2];
    const float* W_emb  = (const float*)d_in[3];
    const float* b_emb  = (const float*)d_in[4];
    const float* W1     = (const float*)d_in[5];
    const float* as1    = (const float*)d_in[6];
    const float* ad1    = (const float*)d_in[7];
    const float* b1     = (const float*)d_in[8];
    const float* W2     = (const float*)d_in[9];
    const float* as2    = (const float*)d_in[10];
    const float* ad2    = (const float*)d_in[11];
    const float* b2     = (const float*)d_in[12];
    const float* W3     = (const float*)d_in[13];
    const float* as3    = (const float*)d_in[14];
    const float* ad3    = (const float*)d_in[15];
    const float* b3     = (const float*)d_in[16];
    const float* Wc1    = (const float*)d_in[17];
    const float* bc1    = (const float*)d_in[18];
    const float* Wc2    = (const float*)d_in[19];
    const float* bc2    = (const float*)d_in[20];

    const int N = in_sizes[0] / F_IN;   // 50000
    const int E = in_sizes[1] / 2;      // 800000
    const int ET = E + N;               // with self-loops

    // workspace carve-up (256B aligned)
    size_t off = 0;
    auto alloc = [&](size_t bytes) -> void* {
        void* p = (char*)d_ws + off;
        off += (bytes + 255) & ~(size_t)255;
        return p;
    };
    float*    A       = (float*)alloc((size_t)N * 64 * 4);    // h0 / agg3 out
    float*    B       = (float*)alloc((size_t)N * 256 * 4);   // gemm outputs
    float*    C       = (float*)alloc((size_t)N * 256 * 4);   // agg outputs
    float*    S       = (float*)alloc((size_t)N * 4 * 4);
    float*    D       = (float*)alloc((size_t)N * 4 * 4);
    int*      offs    = (int*)alloc((size_t)(N + 1) * 4);
    int*      cnt     = (int*)alloc((size_t)N * 4);           // also cursor
    int*      bsum    = (int*)alloc(64 * 4);
    int*      csr_src = (int*)alloc((size_t)ET * 4);
    float*    gsum    = (float*)alloc(NG * 64 * 4);
    unsigned* gmax    = (unsigned*)alloc(NG * 64 * 4);
    int*      gcnt    = (int*)alloc(NG * 4);
    (void)ws_size; (void)n_in; (void)out_size;

    const int SCB = (N + 1023) / 1024;

    // CSR build
    hipMemsetAsync(cnt, 0, (size_t)N * 4, stream);
    hist_kernel<<<(ET + 255) / 256, 256, 0, stream>>>(ei, cnt, E, N);
    scan1_kernel<<<SCB, 256, 0, stream>>>(cnt, offs, bsum, N);
    scan2_kernel<<<1, 64, 0, stream>>>(bsum, offs, SCB, N);
    scan3_kernel<<<SCB, 256, 0, stream>>>(offs, bsum, N);
    hipMemsetAsync(cnt, 0, (size_t)N * 4, stream);
    scatter_kernel<<<(ET + 255) / 256, 256, 0, stream>>>(ei, offs, cnt, csr_src, E, N);

    const int NWV = (N * 64 + 255) / 256;  // one wave per node kernels
    dim3 gN64((N + 63) / 64, 1);
    dim3 gN256((N + 63) / 64, 4);

    // embedding (no attn epilogue)
    gemm_f32<128><<<gN64, 256, 0, stream>>>(x, W_emb, A, N, 64, b_emb,
                                            nullptr, nullptr, nullptr, nullptr, 0);
    // GAT layer 1
    gemm_f32<64><<<gN256, 256, 0, stream>>>(A, W1, B, N, 256, nullptr,
                                            as1, ad1, S, D, 4);
    gat_agg<4><<<NWV, 256, 0, stream>>>(B, S, D, offs, csr_src, b1, C, N);
    // GAT layer 2
    gemm_f32<256><<<gN256, 256, 0, stream>>>(C, W2, B, N, 256, nullptr,
                                             as2, ad2, S, D, 4);
    gat_agg<4><<<NWV, 256, 0, stream>>>(B, S, D, offs, csr_src, b2, C, N);
    // GAT layer 3 (1 head)
    gemm_f32<256><<<gN64, 256, 0, stream>>>(C, W3, B, N, 64, nullptr,
                                            as3, ad3, S, D, 1);
    gat_agg<1><<<NWV, 256, 0, stream>>>(B, S, D, offs, csr_src, b3, A, N);

    // pooling + classifier
    pool_init<<<16, 256, 0, stream>>>(gsum, gmax, gcnt);
    int per = (N + 255) / 256;  // 256 waves
    pool_reduce<<<64, 256, 0, stream>>>(A, batch, gsum, gmax, gcnt, N, per);
    classifier<<<NG, 128, 0, stream>>>(gsum, gmax, gcnt, Wc1, bc1, Wc2, bc2, (float*)d_out);
}

// Round 4
// 711.711 us; speedup vs baseline: 1.2550x; 1.0785x over previous
//
#include <hip/hip_runtime.h>
#include <math.h>

#define NG 64          // graphs
#define F_IN 128
#define NEG_SLOPE 0.2f

typedef __attribute__((ext_vector_type(8))) short s16x8;
typedef __attribute__((ext_vector_type(4))) float f32x4;

// ---------- helpers ----------
static __device__ __forceinline__ float elu_f(float x) { return x > 0.f ? x : expm1f(x); }
static __device__ __forceinline__ float lrelu(float x) { return x > 0.f ? x : NEG_SLOPE * x; }
static __device__ __forceinline__ unsigned enc_f32(float x) {
    unsigned u = __float_as_uint(x);
    return (u & 0x80000000u) ? ~u : (u | 0x80000000u);
}
static __device__ __forceinline__ float dec_f32(unsigned u) {
    unsigned b = (u & 0x80000000u) ? (u & 0x7fffffffu) : ~u;
    return __uint_as_float(b);
}
static __device__ __forceinline__ unsigned short bf16_rn(float x) {
    unsigned u = __float_as_uint(x);
    unsigned r = u + 0x7FFFu + ((u >> 16) & 1u);
    return (unsigned short)(r >> 16);
}
static __device__ __forceinline__ float bf16_to_f32(unsigned short h) {
    return __uint_as_float(((unsigned)h) << 16);
}

// ---------- CSR build ----------
__global__ void hist_kernel(const int* __restrict__ ei, int* __restrict__ cnt, int E, int N) {
    int e = blockIdx.x * blockDim.x + threadIdx.x;
    int ET = E + N;
    if (e >= ET) return;
    int dst = (e < E) ? ei[E + e] : (e - E);   // self-loops appended
    atomicAdd(&cnt[dst], 1);
}

__global__ void scan1_kernel(const int* __restrict__ cnt, int* __restrict__ excl,
                             int* __restrict__ bsum, int n) {
    __shared__ int sm[256];
    int t = threadIdx.x;
    int base = blockIdx.x * 1024 + t * 4;
    int v[4];
    #pragma unroll
    for (int u = 0; u < 4; ++u) { int idx = base + u; v[u] = (idx < n) ? cnt[idx] : 0; }
    int tsum = v[0] + v[1] + v[2] + v[3];
    sm[t] = tsum;
    __syncthreads();
    for (int off = 1; off < 256; off <<= 1) {
        int y = (t >= off) ? sm[t - off] : 0;
        __syncthreads();
        sm[t] += y;
        __syncthreads();
    }
    int run = sm[t] - tsum;  // exclusive base for this thread
    #pragma unroll
    for (int u = 0; u < 4; ++u) {
        int idx = base + u;
        if (idx < n) excl[idx] = run;
        run += v[u];
    }
    if (t == 255) bsum[blockIdx.x] = sm[255];
}

__global__ void scan2_kernel(int* __restrict__ bsum, int* __restrict__ offs, int nb, int n) {
    if (blockIdx.x == 0 && threadIdx.x == 0) {
        int run = 0;
        for (int b = 0; b < nb; ++b) { int t = bsum[b]; bsum[b] = run; run += t; }
        offs[n] = run;  // grand total = E + N
    }
}

__global__ void scan3_kernel(int* __restrict__ offs, const int* __restrict__ bsum, int n) {
    int base = blockIdx.x * 1024 + threadIdx.x * 4;
    int add = bsum[blockIdx.x];
    #pragma unroll
    for (int u = 0; u < 4; ++u) { int idx = base + u; if (idx < n) offs[idx] += add; }
}

__global__ void scatter_kernel(const int* __restrict__ ei, const int* __restrict__ offs,
                               int* __restrict__ cursor, int* __restrict__ csr_src, int E, int N) {
    int e = blockIdx.x * blockDim.x + threadIdx.x;
    int ET = E + N;
    if (e >= ET) return;
    int src, dst;
    if (e < E) { src = ei[e]; dst = ei[E + e]; }
    else       { src = e - E; dst = e - E; }
    int pos = offs[dst] + atomicAdd(&cursor[dst], 1);
    csr_src[pos] = src;
}

// ---------- split-bf16 MFMA GEMM ----------
// Out[n][m] = dot(A[n][:K], W[m][:K]) + bias[m]     (error ~2^-18 via hi/lo split)
// BM=64 rows/block, BN cols/block, 256 threads = 4 waves, wave owns 16 rows x BN cols.
// Optional fused attention epilogue: S[n*H+h], D[n*H+h], H = BN/64.
template<int K, int BN>
__global__ __launch_bounds__(256) void gemm_mfma(const float* __restrict__ A,
                                                 const float* __restrict__ W,
                                                 float* __restrict__ Out,
                                                 int N, int M, const float* __restrict__ bias,
                                                 const float* __restrict__ asrc,
                                                 const float* __restrict__ adst,
                                                 float* __restrict__ S, float* __restrict__ D) {
    const int NC = BN / 16;            // col fragments per wave
    const int H = BN / 64;             // heads covered by this block
    __shared__ __align__(16) unsigned short As_hi[64][40];
    __shared__ __align__(16) unsigned short As_lo[64][40];
    __shared__ __align__(16) unsigned short Bs_hi[BN][40];
    __shared__ __align__(16) unsigned short Bs_lo[BN][40];

    const int t = threadIdx.x;
    const int lane = t & 63;
    const int w = t >> 6;              // wave id 0..3
    const int wr0 = w * 16;            // wave's row offset in tile
    const int n0 = blockIdx.x * 64;
    const int m0 = blockIdx.y * BN;
    const int lj = lane & 15;
    const int kg = lane >> 4;          // k-group 0..3 (k = kg*8 + e)

    f32x4 acc[NC];
    #pragma unroll
    for (int c = 0; c < NC; ++c) acc[c] = (f32x4){0.f, 0.f, 0.f, 0.f};

    for (int kc = 0; kc < K; kc += 32) {
        __syncthreads();
        // stage A: 64 rows x 32 k (each thread: 8 consecutive floats)
        {
            int row = t >> 2, seg = t & 3;
            int gr = n0 + row;
            float v[8];
            if (gr < N) {
                float4 v0 = *(const float4*)&A[(size_t)gr * K + kc + seg * 8];
                float4 v1 = *(const float4*)&A[(size_t)gr * K + kc + seg * 8 + 4];
                v[0]=v0.x; v[1]=v0.y; v[2]=v0.z; v[3]=v0.w;
                v[4]=v1.x; v[5]=v1.y; v[6]=v1.z; v[7]=v1.w;
            } else {
                #pragma unroll
                for (int u = 0; u < 8; ++u) v[u] = 0.f;
            }
            uint4 hp, lp;
            unsigned hw[4], lw[4];
            #pragma unroll
            for (int p = 0; p < 4; ++p) {
                unsigned short h0 = bf16_rn(v[2*p]),   h1 = bf16_rn(v[2*p+1]);
                unsigned short l0 = bf16_rn(v[2*p]   - bf16_to_f32(h0));
                unsigned short l1 = bf16_rn(v[2*p+1] - bf16_to_f32(h1));
                hw[p] = (unsigned)h0 | ((unsigned)h1 << 16);
                lw[p] = (unsigned)l0 | ((unsigned)l1 << 16);
            }
            hp = make_uint4(hw[0], hw[1], hw[2], hw[3]);
            lp = make_uint4(lw[0], lw[1], lw[2], lw[3]);
            *(uint4*)&As_hi[row][seg * 8] = hp;
            *(uint4*)&As_lo[row][seg * 8] = lp;
        }
        // stage B (W): BN rows x 32 k
        #pragma unroll
        for (int it = 0; it < BN / 64; ++it) {
            int row = (t >> 2) + it * 64, seg = t & 3;
            float4 v0 = *(const float4*)&W[(size_t)(m0 + row) * K + kc + seg * 8];
            float4 v1 = *(const float4*)&W[(size_t)(m0 + row) * K + kc + seg * 8 + 4];
            float v[8] = {v0.x, v0.y, v0.z, v0.w, v1.x, v1.y, v1.z, v1.w};
            unsigned hw[4], lw[4];
            #pragma unroll
            for (int p = 0; p < 4; ++p) {
                unsigned short h0 = bf16_rn(v[2*p]),   h1 = bf16_rn(v[2*p+1]);
                unsigned short l0 = bf16_rn(v[2*p]   - bf16_to_f32(h0));
                unsigned short l1 = bf16_rn(v[2*p+1] - bf16_to_f32(h1));
                hw[p] = (unsigned)h0 | ((unsigned)h1 << 16);
                lw[p] = (unsigned)l0 | ((unsigned)l1 << 16);
            }
            *(uint4*)&Bs_hi[row][seg * 8] = make_uint4(hw[0], hw[1], hw[2], hw[3]);
            *(uint4*)&Bs_lo[row][seg * 8] = make_uint4(lw[0], lw[1], lw[2], lw[3]);
        }
        __syncthreads();

        // fragments + MFMA
        s16x8 ah = *(const s16x8*)&As_hi[wr0 + lj][kg * 8];
        s16x8 al = *(const s16x8*)&As_lo[wr0 + lj][kg * 8];
        #pragma unroll
        for (int c = 0; c < NC; ++c) {
            s16x8 bh = *(const s16x8*)&Bs_hi[c * 16 + lj][kg * 8];
            s16x8 bl = *(const s16x8*)&Bs_lo[c * 16 + lj][kg * 8];
            acc[c] = __builtin_amdgcn_mfma_f32_16x16x32_bf16(ah, bh, acc[c], 0, 0, 0);
            acc[c] = __builtin_amdgcn_mfma_f32_16x16x32_bf16(ah, bl, acc[c], 0, 0, 0);
            acc[c] = __builtin_amdgcn_mfma_f32_16x16x32_bf16(al, bh, acc[c], 0, 0, 0);
        }
    }

    // epilogue: C/D layout col=lane&15, row=(lane>>4)*4+reg
    #pragma unroll
    for (int c = 0; c < NC; ++c) {
        float bv = bias ? bias[m0 + c * 16 + lj] : 0.f;
        #pragma unroll
        for (int r = 0; r < 4; ++r) {
            int gn = n0 + wr0 + (lane >> 4) * 4 + r;
            if (gn < N) Out[(size_t)gn * M + m0 + c * 16 + lj] = acc[c][r] + bv;
        }
    }
    // fused attention scalars
    if (asrc) {
        #pragma unroll
        for (int hh = 0; hh < H; ++hh) {
            float aw[4], dw[4];
            #pragma unroll
            for (int c2 = 0; c2 < 4; ++c2) {
                aw[c2] = asrc[hh * 64 + c2 * 16 + lj];
                dw[c2] = adst[hh * 64 + c2 * 16 + lj];
            }
            #pragma unroll
            for (int r = 0; r < 4; ++r) {
                float sp = 0.f, dp = 0.f;
                #pragma unroll
                for (int c2 = 0; c2 < 4; ++c2) {
                    int c = hh * 4 + c2;
                    sp = fmaf(acc[c][r], aw[c2], sp);
                    dp = fmaf(acc[c][r], dw[c2], dp);
                }
                #pragma unroll
                for (int off = 1; off < 16; off <<= 1) {
                    sp += __shfl_xor(sp, off);
                    dp += __shfl_xor(dp, off);
                }
                if (lj == 0) {
                    int gn = n0 + wr0 + (lane >> 4) * 4 + r;
                    if (gn < N) { S[gn * H + hh] = sp; D[gn * H + hh] = dp; }
                }
            }
        }
    }
}

// ---------- GAT aggregation: one wave per dst node, chunked online softmax ----------
template<int H>  // H=4 -> HC=256 (lane owns 4 chans), H=1 -> HC=64 (lane owns 1)
__global__ __launch_bounds__(256, 8) void gat_agg(const float* __restrict__ hL,
                                                  const float* __restrict__ s,
                                                  const float* __restrict__ d,
                                                  const int* __restrict__ offs,
                                                  const int* __restrict__ csr_src,
                                                  const float* __restrict__ bias,
                                                  float* __restrict__ out, int N) {
    const int HC = H * 64;
    const int SW = (H == 4) ? 5 : 2;     // stash words per edge
    __shared__ float stash[4][64 * 5];   // per-wave slice; no cross-wave sharing -> no barrier
    int wv = threadIdx.x >> 6;
    int lane = threadIdx.x & 63;
    int node = (blockIdx.x * blockDim.x + threadIdx.x) >> 6;
    if (node >= N) return;
    float* st = stash[wv];
    int e0 = offs[node], e1 = offs[node + 1];

    float dd[H];
    #pragma unroll
    for (int h = 0; h < H; ++h) dd[h] = d[node * H + h];

    const int hd = (H == 4) ? (lane >> 4) : 0;

    float mrun = -INFINITY;
    float acc0 = 0.f, acc1 = 0.f, acc2 = 0.f, acc3 = 0.f, den = 0.f;

    for (int base = e0; base < e1; base += 64) {
        int cnt = min(64, e1 - base);
        float ev[H];
        #pragma unroll
        for (int h = 0; h < H; ++h) ev[h] = -INFINITY;
        if (lane < cnt) {
            int src = csr_src[base + lane];
            if (H == 4) {
                float4 sv = *(const float4*)&s[src * 4];
                ev[0] = lrelu(sv.x + dd[0]); ev[1] = lrelu(sv.y + dd[1]);
                ev[2] = lrelu(sv.z + dd[2]); ev[3] = lrelu(sv.w + dd[3]);
                st[lane * 5 + 0] = ev[0]; st[lane * 5 + 1] = ev[1];
                st[lane * 5 + 2] = ev[2]; st[lane * 5 + 3] = ev[3];
                st[lane * 5 + 4] = __int_as_float(src);
            } else {
                ev[0] = lrelu(s[src] + dd[0]);
                st[lane * 2 + 0] = ev[0];
                st[lane * 2 + 1] = __int_as_float(src);
            }
        }
        float mc[H];
        #pragma unroll
        for (int h = 0; h < H; ++h) {
            float m = ev[h];
            #pragma unroll
            for (int off = 32; off; off >>= 1) m = fmaxf(m, __shfl_xor(m, off));
            mc[h] = m;
        }
        float mch = mc[0];
        if (H == 4)
            mch = (lane & 32) ? ((lane & 16) ? mc[3] : mc[2]) : ((lane & 16) ? mc[1] : mc[0]);
        float mnew = fmaxf(mrun, mch);
        float scale = __expf(mrun - mnew);
        acc0 *= scale; acc1 *= scale; acc2 *= scale; acc3 *= scale; den *= scale;
        mrun = mnew;

        int k = 0;
        for (; k + 4 <= cnt; k += 4) {
            float ea = st[(k + 0) * SW + hd];
            float eb = st[(k + 1) * SW + hd];
            float ec = st[(k + 2) * SW + hd];
            float ed = st[(k + 3) * SW + hd];
            int sa = __float_as_int(st[(k + 0) * SW + SW - 1]);
            int sb = __float_as_int(st[(k + 1) * SW + SW - 1]);
            int sc = __float_as_int(st[(k + 2) * SW + SW - 1]);
            int sd_ = __float_as_int(st[(k + 3) * SW + SW - 1]);
            float pa = __expf(ea - mrun);
            float pb = __expf(eb - mrun);
            float pc = __expf(ec - mrun);
            float pd = __expf(ed - mrun);
            den += (pa + pb) + (pc + pd);
            if (H == 4) {
                float4 ha = *(const float4*)&hL[(size_t)sa * 256 + lane * 4];
                float4 hb = *(const float4*)&hL[(size_t)sb * 256 + lane * 4];
                float4 hc = *(const float4*)&hL[(size_t)sc * 256 + lane * 4];
                float4 hdv = *(const float4*)&hL[(size_t)sd_ * 256 + lane * 4];
                acc0 = fmaf(pa, ha.x, acc0); acc1 = fmaf(pa, ha.y, acc1);
                acc2 = fmaf(pa, ha.z, acc2); acc3 = fmaf(pa, ha.w, acc3);
                acc0 = fmaf(pb, hb.x, acc0); acc1 = fmaf(pb, hb.y, acc1);
                acc2 = fmaf(pb, hb.z, acc2); acc3 = fmaf(pb, hb.w, acc3);
                acc0 = fmaf(pc, hc.x, acc0); acc1 = fmaf(pc, hc.y, acc1);
                acc2 = fmaf(pc, hc.z, acc2); acc3 = fmaf(pc, hc.w, acc3);
                acc0 = fmaf(pd, hdv.x, acc0); acc1 = fmaf(pd, hdv.y, acc1);
                acc2 = fmaf(pd, hdv.z, acc2); acc3 = fmaf(pd, hdv.w, acc3);
            } else {
                float ha = hL[(size_t)sa * 64 + lane];
                float hb = hL[(size_t)sb * 64 + lane];
                float hc = hL[(size_t)sc * 64 + lane];
                float hdv = hL[(size_t)sd_ * 64 + lane];
                acc0 = fmaf(pa, ha, acc0);
                acc0 = fmaf(pb, hb, acc0);
                acc0 = fmaf(pc, hc, acc0);
                acc0 = fmaf(pd, hdv, acc0);
            }
        }
        for (; k < cnt; ++k) {
            float e = st[k * SW + hd];
            int src = __float_as_int(st[k * SW + SW - 1]);
            float p = __expf(e - mrun);
            den += p;
            if (H == 4) {
                float4 hv = *(const float4*)&hL[(size_t)src * 256 + lane * 4];
                acc0 = fmaf(p, hv.x, acc0); acc1 = fmaf(p, hv.y, acc1);
                acc2 = fmaf(p, hv.z, acc2); acc3 = fmaf(p, hv.w, acc3);
            } else {
                float hv = hL[(size_t)src * 64 + lane];
                acc0 = fmaf(p, hv, acc0);
            }
        }
    }

    float inv = 1.0f / (den + 1e-16f);
    if (H == 4) {
        float4 bv = *(const float4*)&bias[lane * 4];
        float4 o;
        o.x = elu_f(acc0 * inv + bv.x); o.y = elu_f(acc1 * inv + bv.y);
        o.z = elu_f(acc2 * inv + bv.z); o.w = elu_f(acc3 * inv + bv.w);
        *(float4*)&out[(size_t)node * 256 + lane * 4] = o;
    } else {
        out[(size_t)node * 64 + lane] = elu_f(acc0 * inv + bias[lane]);
    }
}

// ---------- pooling ----------
__global__ void pool_init(float* gsum, unsigned* gmax, int* gcnt) {
    int t = blockIdx.x * blockDim.x + threadIdx.x;
    if (t < NG * 64) { gsum[t] = 0.f; gmax[t] = enc_f32(-INFINITY); }
    if (t < NG) gcnt[t] = 0;
}

__global__ void pool_reduce(const float* __restrict__ h3, const int* __restrict__ batch,
                            float* __restrict__ gsum, unsigned* __restrict__ gmax,
                            int* __restrict__ gcnt, int N, int per) {
    int w = (blockIdx.x * blockDim.x + threadIdx.x) >> 6;
    int lane = threadIdx.x & 63;
    int n0 = w * per;
    int n1 = min(N, n0 + per);
    float lsum = 0.f, lmax = -INFINITY;
    int cur = -1, cnt = 0;
    for (int n = n0; n < n1; ++n) {
        int g = batch[n];
        if (g != cur) {
            if (cur >= 0) {
                atomicAdd(&gsum[cur * 64 + lane], lsum);
                atomicMax(&gmax[cur * 64 + lane], enc_f32(lmax));
                if (lane == 0) atomicAdd(&gcnt[cur], cnt);
            }
            cur = g; lsum = 0.f; lmax = -INFINITY; cnt = 0;
        }
        float v = h3[(size_t)n * 64 + lane];
        lsum += v; lmax = fmaxf(lmax, v); cnt++;
    }
    if (cur >= 0) {
        atomicAdd(&gsum[cur * 64 + lane], lsum);
        atomicMax(&gmax[cur * 64 + lane], enc_f32(lmax));
        if (lane == 0) atomicAdd(&gcnt[cur], cnt);
    }
}

// ---------- classifier: one block per graph ----------
__global__ __launch_bounds__(128) void classifier(const float* __restrict__ gsum,
                                                  const unsigned* __restrict__ gmax,
                                                  const int* __restrict__ gcnt,
                                                  const float* __restrict__ Wc1,
                                                  const float* __restrict__ bc1,
                                                  const float* __restrict__ Wc2,
                                                  const float* __restrict__ bc2,
                                                  float* __restrict__ out) {
    __shared__ float gv[128];
    __shared__ float z1[64];
    int g = blockIdx.x, t = threadIdx.x;
    int cnt = gcnt[g];
    if (t < 64) {
        gv[t] = gsum[g * 64 + t] / fmaxf((float)cnt, 1.f);
    } else {
        float mx = dec_f32(gmax[g * 64 + (t - 64)]);
        gv[t] = (cnt > 0) ? mx : 0.f;
    }
    __syncthreads();
    if (t < 64) {
        float a = bc1[t];
        for (int k = 0; k < 128; ++k) a = fmaf(Wc1[t * 128 + k], gv[k], a);
        z1[t] = a > 0.f ? a : 0.f;
    }
    __syncthreads();
    if (t < 10) {
        float a = bc2[t];
        for (int k = 0; k < 64; ++k) a = fmaf(Wc2[t * 64 + k], z1[k], a);
        out[g * 10 + t] = a;
    }
}

// ---------- launch ----------
extern "C" void kernel_launch(void* const* d_in, const int* in_sizes, int n_in,
                              void* d_out, int out_size, void* d_ws, size_t ws_size,
                              hipStream_t stream) {
    const float* x      = (const float*)d_in[0];
    const int*   ei     = (const int*)d_in[1];
    const int*   batch  = (const int*)d_in[2];
    const float* W_emb  = (const float*)d_in[3];
    const float* b_emb  = (const float*)d_in[4];
    const float* W1     = (const float*)d_in[5];
    const float* as1    = (const float*)d_in[6];
    const float* ad1    = (const float*)d_in[7];
    const float* b1     = (const float*)d_in[8];
    const float* W2     = (const float*)d_in[9];
    const float* as2    = (const float*)d_in[10];
    const float* ad2    = (const float*)d_in[11];
    const float* b2     = (const float*)d_in[12];
    const float* W3     = (const float*)d_in[13];
    const float* as3    = (const float*)d_in[14];
    const float* ad3    = (const float*)d_in[15];
    const float* b3     = (const float*)d_in[16];
    const float* Wc1    = (const float*)d_in[17];
    const float* bc1    = (const float*)d_in[18];
    const float* Wc2    = (const float*)d_in[19];
    const float* bc2    = (const float*)d_in[20];

    const int N = in_sizes[0] / F_IN;   // 50000
    const int E = in_sizes[1] / 2;      // 800000
    const int ET = E + N;               // with self-loops

    // workspace carve-up (256B aligned)
    size_t off = 0;
    auto alloc = [&](size_t bytes) -> void* {
        void* p = (char*)d_ws + off;
        off += (bytes + 255) & ~(size_t)255;
        return p;
    };
    float*    A       = (float*)alloc((size_t)N * 64 * 4);    // h0 / agg3 out
    float*    B       = (float*)alloc((size_t)N * 256 * 4);   // gemm outputs
    float*    C       = (float*)alloc((size_t)N * 256 * 4);   // agg outputs
    float*    S       = (float*)alloc((size_t)N * 4 * 4);
    float*    D       = (float*)alloc((size_t)N * 4 * 4);
    int*      offs    = (int*)alloc((size_t)(N + 1) * 4);
    int*      cnt     = (int*)alloc((size_t)N * 4);           // also cursor
    int*      bsum    = (int*)alloc(64 * 4);
    int*      csr_src = (int*)alloc((size_t)ET * 4);
    float*    gsum    = (float*)alloc(NG * 64 * 4);
    unsigned* gmax    = (unsigned*)alloc(NG * 64 * 4);
    int*      gcnt    = (int*)alloc(NG * 4);
    (void)ws_size; (void)n_in; (void)out_size;

    const int SCB = (N + 1023) / 1024;

    // CSR build
    hipMemsetAsync(cnt, 0, (size_t)N * 4, stream);
    hist_kernel<<<(ET + 255) / 256, 256, 0, stream>>>(ei, cnt, E, N);
    scan1_kernel<<<SCB, 256, 0, stream>>>(cnt, offs, bsum, N);
    scan2_kernel<<<1, 64, 0, stream>>>(bsum, offs, SCB, N);
    scan3_kernel<<<SCB, 256, 0, stream>>>(offs, bsum, N);
    hipMemsetAsync(cnt, 0, (size_t)N * 4, stream);
    scatter_kernel<<<(ET + 255) / 256, 256, 0, stream>>>(ei, offs, cnt, csr_src, E, N);

    const int NWV = (N * 64 + 255) / 256;  // one wave per node kernels
    const int GB = (N + 63) / 64;          // 64-row gemm tiles

    // embedding: M=64, K=128, bias, no attn
    gemm_mfma<128, 64><<<dim3(GB, 1), 256, 0, stream>>>(x, W_emb, A, N, 64, b_emb,
                                                        nullptr, nullptr, nullptr, nullptr);
    // GAT layer 1: M=256, K=64, fused attn (H=4)
    gemm_mfma<64, 256><<<dim3(GB, 1), 256, 0, stream>>>(A, W1, B, N, 256, nullptr,
                                                        as1, ad1, S, D);
    gat_agg<4><<<NWV, 256, 0, stream>>>(B, S, D, offs, csr_src, b1, C, N);
    // GAT layer 2: M=256, K=256, fused attn (H=4)
    gemm_mfma<256, 256><<<dim3(GB, 1), 256, 0, stream>>>(C, W2, B, N, 256, nullptr,
                                                         as2, ad2, S, D);
    gat_agg<4><<<NWV, 256, 0, stream>>>(B, S, D, offs, csr_src, b2, C, N);
    // GAT layer 3: M=64, K=256, fused attn (H=1)
    gemm_mfma<256, 64><<<dim3(GB, 1), 256, 0, stream>>>(C, W3, B, N, 64, nullptr,
                                                        as3, ad3, S, D);
    gat_agg<1><<<NWV, 256, 0, stream>>>(B, S, D, offs, csr_src, b3, A, N);

    // pooling + classifier
    pool_init<<<16, 256, 0, stream>>>(gsum, gmax, gcnt);
    int per = (N + 255) / 256;  // 256 waves
    pool_reduce<<<64, 256, 0, stream>>>(A, batch, gsum, gmax, gcnt, N, per);
    classifier<<<NG, 128, 0, stream>>>(gsum, gmax, gcnt, Wc1, bc1, Wc2, bc2, (float*)d_out);
}

// Round 5
// 630.858 us; speedup vs baseline: 1.4159x; 1.1282x over previous
//
#include <hip/hip_runtime.h>
#include <math.h>

#define NG 64          // graphs
#define F_IN 128
#define NEG_SLOPE 0.2f

typedef __attribute__((ext_vector_type(8))) short s16x8;
typedef __attribute__((ext_vector_type(4))) float f32x4;

// ---------- helpers ----------
static __device__ __forceinline__ float elu_f(float x) { return x > 0.f ? x : expm1f(x); }
static __device__ __forceinline__ float lrelu(float x) { return x > 0.f ? x : NEG_SLOPE * x; }
static __device__ __forceinline__ unsigned enc_f32(float x) {
    unsigned u = __float_as_uint(x);
    return (u & 0x80000000u) ? ~u : (u | 0x80000000u);
}
static __device__ __forceinline__ float dec_f32(unsigned u) {
    unsigned b = (u & 0x80000000u) ? (u & 0x7fffffffu) : ~u;
    return __uint_as_float(b);
}
static __device__ __forceinline__ unsigned short bf16_rn(float x) {
    unsigned u = __float_as_uint(x);
    unsigned r = u + 0x7FFFu + ((u >> 16) & 1u);
    return (unsigned short)(r >> 16);
}
static __device__ __forceinline__ float bf16_to_f32(unsigned short h) {
    return __uint_as_float(((unsigned)h) << 16);
}
static __device__ __forceinline__ unsigned pack_split(float x) {
    unsigned short hi = bf16_rn(x);
    unsigned short lo = bf16_rn(x - bf16_to_f32(hi));
    return ((unsigned)hi << 16) | lo;
}

// ---------- weight pre-pack ----------
__global__ void convert_pack(const float* __restrict__ in, unsigned* __restrict__ out, int n) {
    int idx = (blockIdx.x * blockDim.x + threadIdx.x) * 4;
    if (idx + 3 < n) {
        float4 v = *(const float4*)&in[idx];
        uint4 o;
        o.x = pack_split(v.x); o.y = pack_split(v.y);
        o.z = pack_split(v.z); o.w = pack_split(v.w);
        *(uint4*)&out[idx] = o;
    }
}

// u[h][i] = sum_o W1[h*64+o][i] * a[h][o]   (for layer-1 commute attention scalars)
__global__ void uvec_kernel(const float* __restrict__ W1, const float* __restrict__ a1s,
                            const float* __restrict__ a1d,
                            float* __restrict__ us, float* __restrict__ ud) {
    int h = threadIdx.x >> 6;
    int i = threadIdx.x & 63;
    float s = 0.f, d = 0.f;
    for (int o = 0; o < 64; ++o) {
        float w = W1[(h * 64 + o) * 64 + i];
        s = fmaf(w, a1s[h * 64 + o], s);
        d = fmaf(w, a1d[h * 64 + o], d);
    }
    us[h * 64 + i] = s;
    ud[h * 64 + i] = d;
}

// ---------- CSR build ----------
__global__ void hist_kernel(const int* __restrict__ ei, int* __restrict__ cnt, int E, int N) {
    int e = blockIdx.x * blockDim.x + threadIdx.x;
    int ET = E + N;
    if (e >= ET) return;
    int dst = (e < E) ? ei[E + e] : (e - E);   // self-loops appended
    atomicAdd(&cnt[dst], 1);
}

__global__ void scan1_kernel(const int* __restrict__ cnt, int* __restrict__ excl,
                             int* __restrict__ bsum, int n) {
    __shared__ int sm[256];
    int t = threadIdx.x;
    int base = blockIdx.x * 1024 + t * 4;
    int v[4];
    #pragma unroll
    for (int u = 0; u < 4; ++u) { int idx = base + u; v[u] = (idx < n) ? cnt[idx] : 0; }
    int tsum = v[0] + v[1] + v[2] + v[3];
    sm[t] = tsum;
    __syncthreads();
    for (int off = 1; off < 256; off <<= 1) {
        int y = (t >= off) ? sm[t - off] : 0;
        __syncthreads();
        sm[t] += y;
        __syncthreads();
    }
    int run = sm[t] - tsum;
    #pragma unroll
    for (int u = 0; u < 4; ++u) {
        int idx = base + u;
        if (idx < n) excl[idx] = run;
        run += v[u];
    }
    if (t == 255) bsum[blockIdx.x] = sm[255];
}

__global__ void scan2_kernel(int* __restrict__ bsum, int* __restrict__ offs, int nb, int n) {
    if (blockIdx.x == 0 && threadIdx.x == 0) {
        int run = 0;
        for (int b = 0; b < nb; ++b) { int t = bsum[b]; bsum[b] = run; run += t; }
        offs[n] = run;
    }
}

__global__ void scan3_kernel(int* __restrict__ offs, const int* __restrict__ bsum, int n) {
    int base = blockIdx.x * 1024 + threadIdx.x * 4;
    int add = bsum[blockIdx.x];
    #pragma unroll
    for (int u = 0; u < 4; ++u) { int idx = base + u; if (idx < n) offs[idx] += add; }
}

__global__ void scatter_kernel(const int* __restrict__ ei, const int* __restrict__ offs,
                               int* __restrict__ cursor, int* __restrict__ csr_src, int E, int N) {
    int e = blockIdx.x * blockDim.x + threadIdx.x;
    int ET = E + N;
    if (e >= ET) return;
    int src, dst;
    if (e < E) { src = ei[e]; dst = ei[E + e]; }
    else       { src = e - E; dst = e - E; }
    int pos = offs[dst] + atomicAdd(&cursor[dst], 1);
    csr_src[pos] = src;
}

// ---------- split-bf16 MFMA GEMM (A f32 on-the-fly split; W pre-packed) ----------
// Out[n][m0+c] = dot(A[n][aoff:aoff+K], Wrow[c]) (+bias) (elu opt)
// SLICED: batched-head mode, grid.y = head; A col offset = y*K, W = Wp + y*BN*K.
// HATT>0: fused attention scalars; SHARED: heads share the block's 64 cols.
template<int K, int BN, int HATT, bool SHARED, bool SLICED, bool DO_ELU>
__global__ __launch_bounds__(256) void gemm_mfma(const float* __restrict__ A, int lda,
                                                 const unsigned* __restrict__ Wp,
                                                 float* __restrict__ Out, int M,
                                                 const float* __restrict__ bias,
                                                 const float* __restrict__ asrc,
                                                 const float* __restrict__ adst,
                                                 float* __restrict__ S, float* __restrict__ D,
                                                 int N) {
    const int NC = BN / 16;
    __shared__ __align__(16) unsigned short As_hi[64][40];
    __shared__ __align__(16) unsigned short As_lo[64][40];
    __shared__ __align__(16) unsigned short Bs_hi[BN][40];
    __shared__ __align__(16) unsigned short Bs_lo[BN][40];

    const int t = threadIdx.x;
    const int lane = t & 63;
    const int w = t >> 6;
    const int wr0 = w * 16;
    const int n0 = blockIdx.x * 64;
    const int m0 = blockIdx.y * BN;
    const int lj = lane & 15;
    const int kg = lane >> 4;
    const int aoff = SLICED ? blockIdx.y * K : 0;
    const unsigned* __restrict__ Wb = SLICED ? (Wp + (size_t)blockIdx.y * BN * K) : Wp;

    f32x4 acc[NC];
    #pragma unroll
    for (int c = 0; c < NC; ++c) acc[c] = (f32x4){0.f, 0.f, 0.f, 0.f};

    for (int kc = 0; kc < K; kc += 32) {
        __syncthreads();
        // stage A (f32 -> split): 64 rows x 32 k, thread handles 8 consecutive
        {
            int row = t >> 2, seg = t & 3;
            int gr = n0 + row;
            float v[8];
            if (gr < N) {
                float4 v0 = *(const float4*)&A[(size_t)gr * lda + aoff + kc + seg * 8];
                float4 v1 = *(const float4*)&A[(size_t)gr * lda + aoff + kc + seg * 8 + 4];
                v[0]=v0.x; v[1]=v0.y; v[2]=v0.z; v[3]=v0.w;
                v[4]=v1.x; v[5]=v1.y; v[6]=v1.z; v[7]=v1.w;
            } else {
                #pragma unroll
                for (int u = 0; u < 8; ++u) v[u] = 0.f;
            }
            unsigned hw[4], lw[4];
            #pragma unroll
            for (int p = 0; p < 4; ++p) {
                unsigned short h0 = bf16_rn(v[2*p]),   h1 = bf16_rn(v[2*p+1]);
                unsigned short l0 = bf16_rn(v[2*p]   - bf16_to_f32(h0));
                unsigned short l1 = bf16_rn(v[2*p+1] - bf16_to_f32(h1));
                hw[p] = (unsigned)h0 | ((unsigned)h1 << 16);
                lw[p] = (unsigned)l0 | ((unsigned)l1 << 16);
            }
            *(uint4*)&As_hi[row][seg * 8] = make_uint4(hw[0], hw[1], hw[2], hw[3]);
            *(uint4*)&As_lo[row][seg * 8] = make_uint4(lw[0], lw[1], lw[2], lw[3]);
        }
        // stage W (packed -> unpack): BN rows x 32 k
        #pragma unroll
        for (int it = 0; it < BN / 64; ++it) {
            int row = (t >> 2) + it * 64, seg = t & 3;
            int wrow = SLICED ? row : (m0 + row);
            uint4 q0 = *(const uint4*)&Wb[(size_t)wrow * K + kc + seg * 8];
            uint4 q1 = *(const uint4*)&Wb[(size_t)wrow * K + kc + seg * 8 + 4];
            unsigned p[8] = {q0.x, q0.y, q0.z, q0.w, q1.x, q1.y, q1.z, q1.w};
            unsigned hw[4], lw[4];
            #pragma unroll
            for (int j = 0; j < 4; ++j) {
                hw[j] = (p[2*j] >> 16) | (p[2*j+1] & 0xffff0000u);
                lw[j] = (p[2*j] & 0xffffu) | (p[2*j+1] << 16);
            }
            *(uint4*)&Bs_hi[row][seg * 8] = make_uint4(hw[0], hw[1], hw[2], hw[3]);
            *(uint4*)&Bs_lo[row][seg * 8] = make_uint4(lw[0], lw[1], lw[2], lw[3]);
        }
        __syncthreads();

        s16x8 ah = *(const s16x8*)&As_hi[wr0 + lj][kg * 8];
        s16x8 al = *(const s16x8*)&As_lo[wr0 + lj][kg * 8];
        #pragma unroll
        for (int c = 0; c < NC; ++c) {
            s16x8 bh = *(const s16x8*)&Bs_hi[c * 16 + lj][kg * 8];
            s16x8 bl = *(const s16x8*)&Bs_lo[c * 16 + lj][kg * 8];
            acc[c] = __builtin_amdgcn_mfma_f32_16x16x32_bf16(ah, bh, acc[c], 0, 0, 0);
            acc[c] = __builtin_amdgcn_mfma_f32_16x16x32_bf16(ah, bl, acc[c], 0, 0, 0);
            acc[c] = __builtin_amdgcn_mfma_f32_16x16x32_bf16(al, bh, acc[c], 0, 0, 0);
        }
    }

    // C/D layout: col = lane&15, row = (lane>>4)*4 + reg
    #pragma unroll
    for (int c = 0; c < NC; ++c) {
        float bv = bias ? bias[m0 + c * 16 + lj] : 0.f;
        #pragma unroll
        for (int r = 0; r < 4; ++r) {
            int gn = n0 + wr0 + (lane >> 4) * 4 + r;
            if (gn < N) {
                float o = acc[c][r] + bv;
                if (DO_ELU) o = elu_f(o);
                Out[(size_t)gn * M + m0 + c * 16 + lj] = o;
            }
        }
    }
    // fused attention scalars (on post-bias values)
    if (HATT > 0) {
        #pragma unroll
        for (int hh = 0; hh < HATT; ++hh) {
            float aw[4], dw[4], bw[4];
            #pragma unroll
            for (int c2 = 0; c2 < 4; ++c2) {
                aw[c2] = asrc[hh * 64 + c2 * 16 + lj];
                dw[c2] = adst[hh * 64 + c2 * 16 + lj];
                int ci = SHARED ? c2 : hh * 4 + c2;
                bw[c2] = bias ? bias[m0 + ci * 16 + lj] : 0.f;
            }
            #pragma unroll
            for (int r = 0; r < 4; ++r) {
                float sp = 0.f, dp = 0.f;
                #pragma unroll
                for (int c2 = 0; c2 < 4; ++c2) {
                    int ci = SHARED ? c2 : hh * 4 + c2;
                    float vv = acc[ci][r] + bw[c2];
                    sp = fmaf(vv, aw[c2], sp);
                    dp = fmaf(vv, dw[c2], dp);
                }
                #pragma unroll
                for (int off = 1; off < 16; off <<= 1) {
                    sp += __shfl_xor(sp, off);
                    dp += __shfl_xor(dp, off);
                }
                if (lj == 0) {
                    int gn = n0 + wr0 + (lane >> 4) * 4 + r;
                    if (gn < N) { S[gn * HATT + hh] = sp; D[gn * HATT + hh] = dp; }
                }
            }
        }
    }
}

// ---------- layer-1 aggregation over raw x (commuted): G[n][h][ch] = sum alpha_h * x_src[ch]
__global__ __launch_bounds__(256, 8) void gat_agg_x(const float* __restrict__ xA,  // [N][64]
                                                    const float* __restrict__ s,   // [N][4]
                                                    const float* __restrict__ d,
                                                    const int* __restrict__ offs,
                                                    const int* __restrict__ csr_src,
                                                    float* __restrict__ G,         // [N][4][64]
                                                    int N) {
    __shared__ float stash[4][64 * 5];
    int wv = threadIdx.x >> 6;
    int lane = threadIdx.x & 63;
    int node = (blockIdx.x * blockDim.x + threadIdx.x) >> 6;
    if (node >= N) return;
    float* st = stash[wv];
    int e0 = offs[node], e1 = offs[node + 1];
    float4 dv4 = *(const float4*)&d[node * 4];
    float dd[4] = {dv4.x, dv4.y, dv4.z, dv4.w};
    float mrun[4] = {-INFINITY, -INFINITY, -INFINITY, -INFINITY};
    float den[4] = {0.f, 0.f, 0.f, 0.f};
    float acc[4] = {0.f, 0.f, 0.f, 0.f};

    for (int base = e0; base < e1; base += 64) {
        int cnt = min(64, e1 - base);
        float ev[4] = {-INFINITY, -INFINITY, -INFINITY, -INFINITY};
        if (lane < cnt) {
            int src = csr_src[base + lane];
            float4 sv = *(const float4*)&s[src * 4];
            ev[0] = lrelu(sv.x + dd[0]); ev[1] = lrelu(sv.y + dd[1]);
            ev[2] = lrelu(sv.z + dd[2]); ev[3] = lrelu(sv.w + dd[3]);
            st[lane * 5 + 0] = ev[0]; st[lane * 5 + 1] = ev[1];
            st[lane * 5 + 2] = ev[2]; st[lane * 5 + 3] = ev[3];
            st[lane * 5 + 4] = __int_as_float(src);
        }
        #pragma unroll
        for (int h = 0; h < 4; ++h) {
            float m = ev[h];
            #pragma unroll
            for (int off = 32; off; off >>= 1) m = fmaxf(m, __shfl_xor(m, off));
            float mnew = fmaxf(mrun[h], m);
            float scale = __expf(mrun[h] - mnew);
            acc[h] *= scale; den[h] *= scale;
            mrun[h] = mnew;
        }
        int k = 0;
        for (; k + 4 <= cnt; k += 4) {
            int si[4];
            #pragma unroll
            for (int u = 0; u < 4; ++u) si[u] = __float_as_int(st[(k + u) * 5 + 4]);
            float vx[4];
            #pragma unroll
            for (int u = 0; u < 4; ++u) vx[u] = xA[(size_t)si[u] * 64 + lane];
            #pragma unroll
            for (int u = 0; u < 4; ++u) {
                #pragma unroll
                for (int h = 0; h < 4; ++h) {
                    float p = __expf(st[(k + u) * 5 + h] - mrun[h]);
                    den[h] += p;
                    acc[h] = fmaf(p, vx[u], acc[h]);
                }
            }
        }
        for (; k < cnt; ++k) {
            int src = __float_as_int(st[k * 5 + 4]);
            float v = xA[(size_t)src * 64 + lane];
            #pragma unroll
            for (int h = 0; h < 4; ++h) {
                float p = __expf(st[k * 5 + h] - mrun[h]);
                den[h] += p;
                acc[h] = fmaf(p, v, acc[h]);
            }
        }
    }
    #pragma unroll
    for (int h = 0; h < 4; ++h)
        G[(size_t)node * 256 + h * 64 + lane] = acc[h] / (den[h] + 1e-16f);
}

// ---------- GAT aggregation (traditional): one wave per dst node, chunked online softmax ----------
template<int H>
__global__ __launch_bounds__(256, 8) void gat_agg(const float* __restrict__ hL,
                                                  const float* __restrict__ s,
                                                  const float* __restrict__ d,
                                                  const int* __restrict__ offs,
                                                  const int* __restrict__ csr_src,
                                                  const float* __restrict__ bias,
                                                  float* __restrict__ out, int N) {
    const int HC = H * 64;
    const int SW = (H == 4) ? 5 : 2;
    __shared__ float stash[4][64 * 5];
    int wv = threadIdx.x >> 6;
    int lane = threadIdx.x & 63;
    int node = (blockIdx.x * blockDim.x + threadIdx.x) >> 6;
    if (node >= N) return;
    float* st = stash[wv];
    int e0 = offs[node], e1 = offs[node + 1];

    float dd[H];
    #pragma unroll
    for (int h = 0; h < H; ++h) dd[h] = d[node * H + h];

    const int hd = (H == 4) ? (lane >> 4) : 0;

    float mrun = -INFINITY;
    float acc0 = 0.f, acc1 = 0.f, acc2 = 0.f, acc3 = 0.f, den = 0.f;

    for (int base = e0; base < e1; base += 64) {
        int cnt = min(64, e1 - base);
        float ev[H];
        #pragma unroll
        for (int h = 0; h < H; ++h) ev[h] = -INFINITY;
        if (lane < cnt) {
            int src = csr_src[base + lane];
            if (H == 4) {
                float4 sv = *(const float4*)&s[src * 4];
                ev[0] = lrelu(sv.x + dd[0]); ev[1] = lrelu(sv.y + dd[1]);
                ev[2] = lrelu(sv.z + dd[2]); ev[3] = lrelu(sv.w + dd[3]);
                st[lane * 5 + 0] = ev[0]; st[lane * 5 + 1] = ev[1];
                st[lane * 5 + 2] = ev[2]; st[lane * 5 + 3] = ev[3];
                st[lane * 5 + 4] = __int_as_float(src);
            } else {
                ev[0] = lrelu(s[src] + dd[0]);
                st[lane * 2 + 0] = ev[0];
                st[lane * 2 + 1] = __int_as_float(src);
            }
        }
        float mc[H];
        #pragma unroll
        for (int h = 0; h < H; ++h) {
            float m = ev[h];
            #pragma unroll
            for (int off = 32; off; off >>= 1) m = fmaxf(m, __shfl_xor(m, off));
            mc[h] = m;
        }
        float mch = mc[0];
        if (H == 4)
            mch = (lane & 32) ? ((lane & 16) ? mc[3] : mc[2]) : ((lane & 16) ? mc[1] : mc[0]);
        float mnew = fmaxf(mrun, mch);
        float scale = __expf(mrun - mnew);
        acc0 *= scale; acc1 *= scale; acc2 *= scale; acc3 *= scale; den *= scale;
        mrun = mnew;

        int k = 0;
        for (; k + 4 <= cnt; k += 4) {
            float ea = st[(k + 0) * SW + hd];
            float eb = st[(k + 1) * SW + hd];
            float ec = st[(k + 2) * SW + hd];
            float ed = st[(k + 3) * SW + hd];
            int sa = __float_as_int(st[(k + 0) * SW + SW - 1]);
            int sb = __float_as_int(st[(k + 1) * SW + SW - 1]);
            int sc = __float_as_int(st[(k + 2) * SW + SW - 1]);
            int sd_ = __float_as_int(st[(k + 3) * SW + SW - 1]);
            float pa = __expf(ea - mrun);
            float pb = __expf(eb - mrun);
            float pc = __expf(ec - mrun);
            float pd = __expf(ed - mrun);
            den += (pa + pb) + (pc + pd);
            if (H == 4) {
                float4 ha = *(const float4*)&hL[(size_t)sa * 256 + lane * 4];
                float4 hb = *(const float4*)&hL[(size_t)sb * 256 + lane * 4];
                float4 hc = *(const float4*)&hL[(size_t)sc * 256 + lane * 4];
                float4 hdv = *(const float4*)&hL[(size_t)sd_ * 256 + lane * 4];
                acc0 = fmaf(pa, ha.x, acc0); acc1 = fmaf(pa, ha.y, acc1);
                acc2 = fmaf(pa, ha.z, acc2); acc3 = fmaf(pa, ha.w, acc3);
                acc0 = fmaf(pb, hb.x, acc0); acc1 = fmaf(pb, hb.y, acc1);
                acc2 = fmaf(pb, hb.z, acc2); acc3 = fmaf(pb, hb.w, acc3);
                acc0 = fmaf(pc, hc.x, acc0); acc1 = fmaf(pc, hc.y, acc1);
                acc2 = fmaf(pc, hc.z, acc2); acc3 = fmaf(pc, hc.w, acc3);
                acc0 = fmaf(pd, hdv.x, acc0); acc1 = fmaf(pd, hdv.y, acc1);
                acc2 = fmaf(pd, hdv.z, acc2); acc3 = fmaf(pd, hdv.w, acc3);
            } else {
                float ha = hL[(size_t)sa * 64 + lane];
                float hb = hL[(size_t)sb * 64 + lane];
                float hc = hL[(size_t)sc * 64 + lane];
                float hdv = hL[(size_t)sd_ * 64 + lane];
                acc0 = fmaf(pa, ha, acc0);
                acc0 = fmaf(pb, hb, acc0);
                acc0 = fmaf(pc, hc, acc0);
                acc0 = fmaf(pd, hdv, acc0);
            }
        }
        for (; k < cnt; ++k) {
            float e = st[k * SW + hd];
            int src = __float_as_int(st[k * SW + SW - 1]);
            float p = __expf(e - mrun);
            den += p;
            if (H == 4) {
                float4 hv = *(const float4*)&hL[(size_t)src * 256 + lane * 4];
                acc0 = fmaf(p, hv.x, acc0); acc1 = fmaf(p, hv.y, acc1);
                acc2 = fmaf(p, hv.z, acc2); acc3 = fmaf(p, hv.w, acc3);
            } else {
                float hv = hL[(size_t)src * 64 + lane];
                acc0 = fmaf(p, hv, acc0);
            }
        }
    }

    float inv = 1.0f / (den + 1e-16f);
    if (H == 4) {
        float4 bv = *(const float4*)&bias[lane * 4];
        float4 o;
        o.x = elu_f(acc0 * inv + bv.x); o.y = elu_f(acc1 * inv + bv.y);
        o.z = elu_f(acc2 * inv + bv.z); o.w = elu_f(acc3 * inv + bv.w);
        *(float4*)&out[(size_t)node * 256 + lane * 4] = o;
    } else {
        out[(size_t)node * 64 + lane] = elu_f(acc0 * inv + bias[lane]);
    }
}

// ---------- pooling ----------
__global__ void pool_init(float* gsum, unsigned* gmax, int* gcnt) {
    int t = blockIdx.x * blockDim.x + threadIdx.x;
    if (t < NG * 64) { gsum[t] = 0.f; gmax[t] = enc_f32(-INFINITY); }
    if (t < NG) gcnt[t] = 0;
}

__global__ void pool_reduce(const float* __restrict__ h3, const int* __restrict__ batch,
                            float* __restrict__ gsum, unsigned* __restrict__ gmax,
                            int* __restrict__ gcnt, int N, int per) {
    int w = (blockIdx.x * blockDim.x + threadIdx.x) >> 6;
    int lane = threadIdx.x & 63;
    int n0 = w * per;
    int n1 = min(N, n0 + per);
    float lsum = 0.f, lmax = -INFINITY;
    int cur = -1, cnt = 0;
    for (int n = n0; n < n1; ++n) {
        int g = batch[n];
        if (g != cur) {
            if (cur >= 0) {
                atomicAdd(&gsum[cur * 64 + lane], lsum);
                atomicMax(&gmax[cur * 64 + lane], enc_f32(lmax));
                if (lane == 0) atomicAdd(&gcnt[cur], cnt);
            }
            cur = g; lsum = 0.f; lmax = -INFINITY; cnt = 0;
        }
        float v = h3[(size_t)n * 64 + lane];
        lsum += v; lmax = fmaxf(lmax, v); cnt++;
    }
    if (cur >= 0) {
        atomicAdd(&gsum[cur * 64 + lane], lsum);
        atomicMax(&gmax[cur * 64 + lane], enc_f32(lmax));
        if (lane == 0) atomicAdd(&gcnt[cur], cnt);
    }
}

// ---------- classifier: one block per graph ----------
__global__ __launch_bounds__(128) void classifier(const float* __restrict__ gsum,
                                                  const unsigned* __restrict__ gmax,
                                                  const int* __restrict__ gcnt,
                                                  const float* __restrict__ Wc1,
                                                  const float* __restrict__ bc1,
                                                  const float* __restrict__ Wc2,
                                                  const float* __restrict__ bc2,
                                                  float* __restrict__ out) {
    __shared__ float gv[128];
    __shared__ float z1[64];
    int g = blockIdx.x, t = threadIdx.x;
    int cnt = gcnt[g];
    if (t < 64) {
        gv[t] = gsum[g * 64 + t] / fmaxf((float)cnt, 1.f);
    } else {
        float mx = dec_f32(gmax[g * 64 + (t - 64)]);
        gv[t] = (cnt > 0) ? mx : 0.f;
    }
    __syncthreads();
    if (t < 64) {
        float a = bc1[t];
        for (int k = 0; k < 128; ++k) a = fmaf(Wc1[t * 128 + k], gv[k], a);
        z1[t] = a > 0.f ? a : 0.f;
    }
    __syncthreads();
    if (t < 10) {
        float a = bc2[t];
        for (int k = 0; k < 64; ++k) a = fmaf(Wc2[t * 64 + k], z1[k], a);
        out[g * 10 + t] = a;
    }
}

// ---------- launch ----------
extern "C" void kernel_launch(void* const* d_in, const int* in_sizes, int n_in,
                              void* d_out, int out_size, void* d_ws, size_t ws_size,
                              hipStream_t stream) {
    const float* x      = (const float*)d_in[0];
    const int*   ei     = (const int*)d_in[1];
    const int*   batch  = (const int*)d_in[2];
    const float* W_emb  = (const float*)d_in[3];
    const float* b_emb  = (const float*)d_in[4];
    const float* W1     = (const float*)d_in[5];
    const float* as1    = (const float*)d_in[6];
    const float* ad1    = (const float*)d_in[7];
    const float* b1     = (const float*)d_in[8];
    const float* W2     = (const float*)d_in[9];
    const float* as2    = (const float*)d_in[10];
    const float* ad2    = (const float*)d_in[11];
    const float* b2     = (const float*)d_in[12];
    const float* W3     = (const float*)d_in[13];
    const float* as3    = (const float*)d_in[14];
    const float* ad3    = (const float*)d_in[15];
    const float* b3     = (const float*)d_in[16];
    const float* Wc1    = (const float*)d_in[17];
    const float* bc1    = (const float*)d_in[18];
    const float* Wc2    = (const float*)d_in[19];
    const float* bc2    = (const float*)d_in[20];

    const int N = in_sizes[0] / F_IN;   // 50000
    const int E = in_sizes[1] / 2;      // 800000
    const int ET = E + N;

    // workspace carve-up (256B aligned)
    size_t off = 0;
    auto alloc = [&](size_t bytes) -> void* {
        void* p = (char*)d_ws + off;
        off += (bytes + 255) & ~(size_t)255;
        return p;
    };
    float*    A       = (float*)alloc((size_t)N * 64 * 4);    // emb out; later h3
    float*    X       = (float*)alloc((size_t)N * 256 * 4);   // G1; later B=h2; later agg3 out
    float*    Y       = (float*)alloc((size_t)N * 256 * 4);   // C; later C2
    float*    S       = (float*)alloc((size_t)N * 4 * 4);
    float*    D       = (float*)alloc((size_t)N * 4 * 4);
    unsigned* Wp_emb  = (unsigned*)alloc(64 * 128 * 4);
    unsigned* Wp1     = (unsigned*)alloc(256 * 64 * 4);
    unsigned* Wp2     = (unsigned*)alloc(256 * 256 * 4);
    unsigned* Wp3     = (unsigned*)alloc(64 * 256 * 4);
    float*    us1     = (float*)alloc(4 * 64 * 4);
    float*    ud1     = (float*)alloc(4 * 64 * 4);
    int*      offs    = (int*)alloc((size_t)(N + 1) * 4);
    int*      cnt     = (int*)alloc((size_t)N * 4);
    int*      bsum    = (int*)alloc(64 * 4);
    int*      csr_src = (int*)alloc((size_t)ET * 4);
    float*    gsum    = (float*)alloc(NG * 64 * 4);
    unsigned* gmax    = (unsigned*)alloc(NG * 64 * 4);
    int*      gcnt    = (int*)alloc(NG * 4);
    (void)ws_size; (void)n_in; (void)out_size;

    const int SCB = (N + 1023) / 1024;

    // weight pre-pack + u-vectors (tiny)
    convert_pack<<<8, 256, 0, stream>>>(W_emb, Wp_emb, 64 * 128);
    convert_pack<<<16, 256, 0, stream>>>(W1, Wp1, 256 * 64);
    convert_pack<<<64, 256, 0, stream>>>(W2, Wp2, 256 * 256);
    convert_pack<<<16, 256, 0, stream>>>(W3, Wp3, 64 * 256);
    uvec_kernel<<<1, 256, 0, stream>>>(W1, as1, ad1, us1, ud1);

    // CSR build
    hipMemsetAsync(cnt, 0, (size_t)N * 4, stream);
    hist_kernel<<<(ET + 255) / 256, 256, 0, stream>>>(ei, cnt, E, N);
    scan1_kernel<<<SCB, 256, 0, stream>>>(cnt, offs, bsum, N);
    scan2_kernel<<<1, 64, 0, stream>>>(bsum, offs, SCB, N);
    scan3_kernel<<<SCB, 256, 0, stream>>>(offs, bsum, N);
    hipMemsetAsync(cnt, 0, (size_t)N * 4, stream);
    scatter_kernel<<<(ET + 255) / 256, 256, 0, stream>>>(ei, offs, cnt, csr_src, E, N);

    const int NWV = (N * 64 + 255) / 256;
    const int GB = (N + 63) / 64;

    // embedding: A = x@W_embT + b_emb, fused s1,d1 = A . u (shared-cols, 4 heads)
    gemm_mfma<128, 64, 4, true, false, false><<<dim3(GB, 1), 256, 0, stream>>>(
        x, 128, Wp_emb, A, 64, b_emb, us1, ud1, S, D, N);
    // layer-1 commuted aggregation over raw embeddings
    gat_agg_x<<<NWV, 256, 0, stream>>>(A, S, D, offs, csr_src, X, N);
    // per-head transform: C[:,h*64:+64] = elu(G1[:,h,:] @ W1_hT + b1)
    gemm_mfma<64, 64, 0, false, true, true><<<dim3(GB, 4), 256, 0, stream>>>(
        X, 256, Wp1, Y, 256, b1, nullptr, nullptr, nullptr, nullptr, N);
    // layer 2: h2 = C@W2T, fused s2,d2
    gemm_mfma<256, 256, 4, false, false, false><<<dim3(GB, 1), 256, 0, stream>>>(
        Y, 256, Wp2, X, 256, nullptr, as2, ad2, S, D, N);
    gat_agg<4><<<NWV, 256, 0, stream>>>(X, S, D, offs, csr_src, b2, Y, N);
    // layer 3: h3 = C2@W3T, fused s3,d3
    gemm_mfma<256, 64, 1, true, false, false><<<dim3(GB, 1), 256, 0, stream>>>(
        Y, 256, Wp3, A, 64, nullptr, as3, ad3, S, D, N);
    gat_agg<1><<<NWV, 256, 0, stream>>>(A, S, D, offs, csr_src, b3, X, N);

    // pooling + classifier
    pool_init<<<16, 256, 0, stream>>>(gsum, gmax, gcnt);
    int per = (N + 255) / 256;
    pool_reduce<<<64, 256, 0, stream>>>(X, batch, gsum, gmax, gcnt, N, per);
    classifier<<<NG, 128, 0, stream>>>(gsum, gmax, gcnt, Wc1, bc1, Wc2, bc2, (float*)d_out);
}

// Round 7
// 564.411 us; speedup vs baseline: 1.5826x; 1.1177x over previous
//
#include <hip/hip_runtime.h>
#include <math.h>

#define NG 64          // graphs
#define F_IN 128
#define NEG_SLOPE 0.2f

typedef __attribute__((ext_vector_type(8))) short s16x8;
typedef __attribute__((ext_vector_type(4))) float f32x4;

// ---------- helpers ----------
static __device__ __forceinline__ float elu_f(float x) { return x > 0.f ? x : expm1f(x); }
static __device__ __forceinline__ float lrelu(float x) { return x > 0.f ? x : NEG_SLOPE * x; }
static __device__ __forceinline__ unsigned enc_f32(float x) {
    unsigned u = __float_as_uint(x);
    return (u & 0x80000000u) ? ~u : (u | 0x80000000u);
}
static __device__ __forceinline__ float dec_f32(unsigned u) {
    unsigned b = (u & 0x80000000u) ? (u & 0x7fffffffu) : ~u;
    return __uint_as_float(b);
}
static __device__ __forceinline__ unsigned short bf16_rn(float x) {
    unsigned u = __float_as_uint(x);
    unsigned r = u + 0x7FFFu + ((u >> 16) & 1u);
    return (unsigned short)(r >> 16);
}
static __device__ __forceinline__ float bf16_to_f32(unsigned short h) {
    return __uint_as_float(((unsigned)h) << 16);
}
static __device__ __forceinline__ unsigned pack_split(float x) {
    unsigned short hi = bf16_rn(x);
    unsigned short lo = bf16_rn(x - bf16_to_f32(hi));
    return ((unsigned)hi << 16) | lo;
}

// ---------- weight pre-pack ----------
__global__ void convert_pack(const float* __restrict__ in, unsigned* __restrict__ out, int n) {
    int idx = (blockIdx.x * blockDim.x + threadIdx.x) * 4;
    if (idx + 3 < n) {
        float4 v = *(const float4*)&in[idx];
        uint4 o;
        o.x = pack_split(v.x); o.y = pack_split(v.y);
        o.z = pack_split(v.z); o.w = pack_split(v.w);
        *(uint4*)&out[idx] = o;
    }
}

// u[h][i] = sum_o W1[h*64+o][i] * a[h][o]   (layer-1 commute attention scalars)
__global__ void uvec_kernel(const float* __restrict__ W1, const float* __restrict__ a1s,
                            const float* __restrict__ a1d,
                            float* __restrict__ us, float* __restrict__ ud) {
    int h = threadIdx.x >> 6;
    int i = threadIdx.x & 63;
    float s = 0.f, d = 0.f;
    for (int o = 0; o < 64; ++o) {
        float w = W1[(h * 64 + o) * 64 + i];
        s = fmaf(w, a1s[h * 64 + o], s);
        d = fmaf(w, a1d[h * 64 + o], d);
    }
    us[h * 64 + i] = s;
    ud[h * 64 + i] = d;
}

// ---------- CSR build ----------
__global__ void hist_kernel(const int* __restrict__ ei, int* __restrict__ cnt, int E, int N) {
    int e = blockIdx.x * blockDim.x + threadIdx.x;
    int ET = E + N;
    if (e >= ET) return;
    int dst = (e < E) ? ei[E + e] : (e - E);
    atomicAdd(&cnt[dst], 1);
}

__global__ void scan1_kernel(const int* __restrict__ cnt, int* __restrict__ excl,
                             int* __restrict__ bsum, int n) {
    __shared__ int sm[256];
    int t = threadIdx.x;
    int base = blockIdx.x * 1024 + t * 4;
    int v[4];
    #pragma unroll
    for (int u = 0; u < 4; ++u) { int idx = base + u; v[u] = (idx < n) ? cnt[idx] : 0; }
    int tsum = v[0] + v[1] + v[2] + v[3];
    sm[t] = tsum;
    __syncthreads();
    for (int off = 1; off < 256; off <<= 1) {
        int y = (t >= off) ? sm[t - off] : 0;
        __syncthreads();
        sm[t] += y;
        __syncthreads();
    }
    int run = sm[t] - tsum;
    #pragma unroll
    for (int u = 0; u < 4; ++u) {
        int idx = base + u;
        if (idx < n) excl[idx] = run;
        run += v[u];
    }
    if (t == 255) bsum[blockIdx.x] = sm[255];
}

__global__ void scan2_kernel(int* __restrict__ bsum, int* __restrict__ offs, int nb, int n) {
    if (blockIdx.x == 0 && threadIdx.x == 0) {
        int run = 0;
        for (int b = 0; b < nb; ++b) { int t = bsum[b]; bsum[b] = run; run += t; }
        offs[n] = run;
    }
}

__global__ void scan3_kernel(int* __restrict__ offs, const int* __restrict__ bsum, int n) {
    int base = blockIdx.x * 1024 + threadIdx.x * 4;
    int add = bsum[blockIdx.x];
    #pragma unroll
    for (int u = 0; u < 4; ++u) { int idx = base + u; if (idx < n) offs[idx] += add; }
}

__global__ void scatter_kernel(const int* __restrict__ ei, const int* __restrict__ offs,
                               int* __restrict__ cursor, int* __restrict__ csr_src, int E, int N) {
    int e = blockIdx.x * blockDim.x + threadIdx.x;
    int ET = E + N;
    if (e >= ET) return;
    int src, dst;
    if (e < E) { src = ei[e]; dst = ei[E + e]; }
    else       { src = e - E; dst = e - E; }
    int pos = offs[dst] + atomicAdd(&cursor[dst], 1);
    csr_src[pos] = src;
}

// ---------- split-bf16 MFMA GEMM (A f32 on-the-fly split; W pre-packed) ----------
// SLICED: batched-head mode, grid.y = head; A col offset = y*K, W = Wp + y*BN*K.
// HATT>0: fused attention scalars; SHARED: heads share the block's 64 cols.
// OUT_BF16: store Out as bf16 (ushort), else f32.
template<int K, int BN, int HATT, bool SHARED, bool SLICED, bool DO_ELU, bool OUT_BF16>
__global__ __launch_bounds__(256) void gemm_mfma(const float* __restrict__ A, int lda,
                                                 const unsigned* __restrict__ Wp,
                                                 void* __restrict__ OutV, int M,
                                                 const float* __restrict__ bias,
                                                 const float* __restrict__ asrc,
                                                 const float* __restrict__ adst,
                                                 float* __restrict__ S, float* __restrict__ D,
                                                 int N) {
    const int NC = BN / 16;
    __shared__ __align__(16) unsigned short As_hi[64][40];
    __shared__ __align__(16) unsigned short As_lo[64][40];
    __shared__ __align__(16) unsigned short Bs_hi[BN][40];
    __shared__ __align__(16) unsigned short Bs_lo[BN][40];

    const int t = threadIdx.x;
    const int lane = t & 63;
    const int w = t >> 6;
    const int wr0 = w * 16;
    const int n0 = blockIdx.x * 64;
    const int m0 = blockIdx.y * BN;
    const int lj = lane & 15;
    const int kg = lane >> 4;
    const int aoff = SLICED ? blockIdx.y * K : 0;
    const unsigned* __restrict__ Wb = SLICED ? (Wp + (size_t)blockIdx.y * BN * K) : Wp;

    f32x4 acc[NC];
    #pragma unroll
    for (int c = 0; c < NC; ++c) acc[c] = (f32x4){0.f, 0.f, 0.f, 0.f};

    for (int kc = 0; kc < K; kc += 32) {
        __syncthreads();
        // stage A (f32 -> split): 64 rows x 32 k
        {
            int row = t >> 2, seg = t & 3;
            int gr = n0 + row;
            float v[8];
            if (gr < N) {
                float4 v0 = *(const float4*)&A[(size_t)gr * lda + aoff + kc + seg * 8];
                float4 v1 = *(const float4*)&A[(size_t)gr * lda + aoff + kc + seg * 8 + 4];
                v[0]=v0.x; v[1]=v0.y; v[2]=v0.z; v[3]=v0.w;
                v[4]=v1.x; v[5]=v1.y; v[6]=v1.z; v[7]=v1.w;
            } else {
                #pragma unroll
                for (int u = 0; u < 8; ++u) v[u] = 0.f;
            }
            unsigned hw[4], lw[4];
            #pragma unroll
            for (int p = 0; p < 4; ++p) {
                unsigned short h0 = bf16_rn(v[2*p]),   h1 = bf16_rn(v[2*p+1]);
                unsigned short l0 = bf16_rn(v[2*p]   - bf16_to_f32(h0));
                unsigned short l1 = bf16_rn(v[2*p+1] - bf16_to_f32(h1));
                hw[p] = (unsigned)h0 | ((unsigned)h1 << 16);
                lw[p] = (unsigned)l0 | ((unsigned)l1 << 16);
            }
            *(uint4*)&As_hi[row][seg * 8] = make_uint4(hw[0], hw[1], hw[2], hw[3]);
            *(uint4*)&As_lo[row][seg * 8] = make_uint4(lw[0], lw[1], lw[2], lw[3]);
        }
        // stage W (packed -> unpack): BN rows x 32 k
        #pragma unroll
        for (int it = 0; it < BN / 64; ++it) {
            int row = (t >> 2) + it * 64, seg = t & 3;
            int wrow = SLICED ? row : (m0 + row);
            uint4 q0 = *(const uint4*)&Wb[(size_t)wrow * K + kc + seg * 8];
            uint4 q1 = *(const uint4*)&Wb[(size_t)wrow * K + kc + seg * 8 + 4];
            unsigned p[8] = {q0.x, q0.y, q0.z, q0.w, q1.x, q1.y, q1.z, q1.w};
            unsigned hw[4], lw[4];
            #pragma unroll
            for (int j = 0; j < 4; ++j) {
                hw[j] = (p[2*j] >> 16) | (p[2*j+1] & 0xffff0000u);
                lw[j] = (p[2*j] & 0xffffu) | (p[2*j+1] << 16);
            }
            *(uint4*)&Bs_hi[row][seg * 8] = make_uint4(hw[0], hw[1], hw[2], hw[3]);
            *(uint4*)&Bs_lo[row][seg * 8] = make_uint4(lw[0], lw[1], lw[2], lw[3]);
        }
        __syncthreads();

        s16x8 ah = *(const s16x8*)&As_hi[wr0 + lj][kg * 8];
        s16x8 al = *(const s16x8*)&As_lo[wr0 + lj][kg * 8];
        #pragma unroll
        for (int c = 0; c < NC; ++c) {
            s16x8 bh = *(const s16x8*)&Bs_hi[c * 16 + lj][kg * 8];
            s16x8 bl = *(const s16x8*)&Bs_lo[c * 16 + lj][kg * 8];
            acc[c] = __builtin_amdgcn_mfma_f32_16x16x32_bf16(ah, bh, acc[c], 0, 0, 0);
            acc[c] = __builtin_amdgcn_mfma_f32_16x16x32_bf16(ah, bl, acc[c], 0, 0, 0);
            acc[c] = __builtin_amdgcn_mfma_f32_16x16x32_bf16(al, bh, acc[c], 0, 0, 0);
        }
    }

    // C/D layout: col = lane&15, row = (lane>>4)*4 + reg
    #pragma unroll
    for (int c = 0; c < NC; ++c) {
        float bv = bias ? bias[m0 + c * 16 + lj] : 0.f;
        #pragma unroll
        for (int r = 0; r < 4; ++r) {
            int gn = n0 + wr0 + (lane >> 4) * 4 + r;
            if (gn < N) {
                float o = acc[c][r] + bv;
                if (DO_ELU) o = elu_f(o);
                if (OUT_BF16)
                    ((unsigned short*)OutV)[(size_t)gn * M + m0 + c * 16 + lj] = bf16_rn(o);
                else
                    ((float*)OutV)[(size_t)gn * M + m0 + c * 16 + lj] = o;
            }
        }
    }
    // fused attention scalars (f32 acc, post-bias)
    if (HATT > 0) {
        #pragma unroll
        for (int hh = 0; hh < HATT; ++hh) {
            float aw[4], dw[4], bw[4];
            #pragma unroll
            for (int c2 = 0; c2 < 4; ++c2) {
                aw[c2] = asrc[hh * 64 + c2 * 16 + lj];
                dw[c2] = adst[hh * 64 + c2 * 16 + lj];
                int ci = SHARED ? c2 : hh * 4 + c2;
                bw[c2] = bias ? bias[m0 + ci * 16 + lj] : 0.f;
            }
            #pragma unroll
            for (int r = 0; r < 4; ++r) {
                float sp = 0.f, dp = 0.f;
                #pragma unroll
                for (int c2 = 0; c2 < 4; ++c2) {
                    int ci = SHARED ? c2 : hh * 4 + c2;
                    float vv = acc[ci][r] + bw[c2];
                    sp = fmaf(vv, aw[c2], sp);
                    dp = fmaf(vv, dw[c2], dp);
                }
                #pragma unroll
                for (int off = 1; off < 16; off <<= 1) {
                    sp += __shfl_xor(sp, off);
                    dp += __shfl_xor(dp, off);
                }
                if (lj == 0) {
                    int gn = n0 + wr0 + (lane >> 4) * 4 + r;
                    if (gn < N) { S[gn * HATT + hh] = sp; D[gn * HATT + hh] = dp; }
                }
            }
        }
    }
}

// ---------- layer-1 aggregation over raw emb (commuted) ----------
__global__ __launch_bounds__(256, 8) void gat_agg_x(const float* __restrict__ xA,  // [N][64]
                                                    const float* __restrict__ s,   // [N][4]
                                                    const float* __restrict__ d,
                                                    const int* __restrict__ offs,
                                                    const int* __restrict__ csr_src,
                                                    float* __restrict__ G,         // [N][4][64]
                                                    int N) {
    __shared__ float stash[4][64 * 5];
    int wv = threadIdx.x >> 6;
    int lane = threadIdx.x & 63;
    int node = (blockIdx.x * blockDim.x + threadIdx.x) >> 6;
    if (node >= N) return;
    float* st = stash[wv];
    int e0 = offs[node], e1 = offs[node + 1];
    float4 dv4 = *(const float4*)&d[node * 4];
    float dd[4] = {dv4.x, dv4.y, dv4.z, dv4.w};
    float mrun[4] = {-INFINITY, -INFINITY, -INFINITY, -INFINITY};
    float den[4] = {0.f, 0.f, 0.f, 0.f};
    float acc[4] = {0.f, 0.f, 0.f, 0.f};

    for (int base = e0; base < e1; base += 64) {
        int cnt = min(64, e1 - base);
        float ev[4] = {-INFINITY, -INFINITY, -INFINITY, -INFINITY};
        if (lane < cnt) {
            int src = csr_src[base + lane];
            float4 sv = *(const float4*)&s[src * 4];
            ev[0] = lrelu(sv.x + dd[0]); ev[1] = lrelu(sv.y + dd[1]);
            ev[2] = lrelu(sv.z + dd[2]); ev[3] = lrelu(sv.w + dd[3]);
            st[lane * 5 + 0] = ev[0]; st[lane * 5 + 1] = ev[1];
            st[lane * 5 + 2] = ev[2]; st[lane * 5 + 3] = ev[3];
            st[lane * 5 + 4] = __int_as_float(src);
        }
        #pragma unroll
        for (int h = 0; h < 4; ++h) {
            float m = ev[h];
            #pragma unroll
            for (int off = 32; off; off >>= 1) m = fmaxf(m, __shfl_xor(m, off));
            float mnew = fmaxf(mrun[h], m);
            float scale = __expf(mrun[h] - mnew);
            acc[h] *= scale; den[h] *= scale;
            mrun[h] = mnew;
        }
        int k = 0;
        for (; k + 4 <= cnt; k += 4) {
            int si[4];
            #pragma unroll
            for (int u = 0; u < 4; ++u) si[u] = __float_as_int(st[(k + u) * 5 + 4]);
            float vx[4];
            #pragma unroll
            for (int u = 0; u < 4; ++u) vx[u] = xA[(size_t)si[u] * 64 + lane];
            #pragma unroll
            for (int u = 0; u < 4; ++u) {
                #pragma unroll
                for (int h = 0; h < 4; ++h) {
                    float p = __expf(st[(k + u) * 5 + h] - mrun[h]);
                    den[h] += p;
                    acc[h] = fmaf(p, vx[u], acc[h]);
                }
            }
        }
        for (; k < cnt; ++k) {
            int src = __float_as_int(st[k * 5 + 4]);
            float v = xA[(size_t)src * 64 + lane];
            #pragma unroll
            for (int h = 0; h < 4; ++h) {
                float p = __expf(st[k * 5 + h] - mrun[h]);
                den[h] += p;
                acc[h] = fmaf(p, v, acc[h]);
            }
        }
    }
    #pragma unroll
    for (int h = 0; h < 4; ++h)
        G[(size_t)node * 256 + h * 64 + lane] = acc[h] / (den[h] + 1e-16f);
}

// ---------- GAT aggregation: one wave per dst node, chunked online softmax ----------
// BF16IN: payload table is bf16 (ushort), unpack on load.
template<int H, bool BF16IN>
__global__ __launch_bounds__(256, 8) void gat_agg(const void* __restrict__ hLV,
                                                  const float* __restrict__ s,
                                                  const float* __restrict__ d,
                                                  const int* __restrict__ offs,
                                                  const int* __restrict__ csr_src,
                                                  const float* __restrict__ bias,
                                                  float* __restrict__ out, int N) {
    const int SW = (H == 4) ? 5 : 2;
    __shared__ float stash[4][64 * 5];
    int wv = threadIdx.x >> 6;
    int lane = threadIdx.x & 63;
    int node = (blockIdx.x * blockDim.x + threadIdx.x) >> 6;
    if (node >= N) return;
    float* st = stash[wv];
    int e0 = offs[node], e1 = offs[node + 1];
    const float* hf = (const float*)hLV;
    const unsigned short* hp = (const unsigned short*)hLV;

    float dd[H];
    #pragma unroll
    for (int h = 0; h < H; ++h) dd[h] = d[node * H + h];

    const int hd = (H == 4) ? (lane >> 4) : 0;

    float mrun = -INFINITY;
    float acc0 = 0.f, acc1 = 0.f, acc2 = 0.f, acc3 = 0.f, den = 0.f;

    for (int base = e0; base < e1; base += 64) {
        int cnt = min(64, e1 - base);
        float ev[H];
        #pragma unroll
        for (int h = 0; h < H; ++h) ev[h] = -INFINITY;
        if (lane < cnt) {
            int src = csr_src[base + lane];
            if (H == 4) {
                float4 sv = *(const float4*)&s[src * 4];
                ev[0] = lrelu(sv.x + dd[0]); ev[1] = lrelu(sv.y + dd[1]);
                ev[2] = lrelu(sv.z + dd[2]); ev[3] = lrelu(sv.w + dd[3]);
                st[lane * 5 + 0] = ev[0]; st[lane * 5 + 1] = ev[1];
                st[lane * 5 + 2] = ev[2]; st[lane * 5 + 3] = ev[3];
                st[lane * 5 + 4] = __int_as_float(src);
            } else {
                ev[0] = lrelu(s[src] + dd[0]);
                st[lane * 2 + 0] = ev[0];
                st[lane * 2 + 1] = __int_as_float(src);
            }
        }
        float mc[H];
        #pragma unroll
        for (int h = 0; h < H; ++h) {
            float m = ev[h];
            #pragma unroll
            for (int off = 32; off; off >>= 1) m = fmaxf(m, __shfl_xor(m, off));
            mc[h] = m;
        }
        float mch = mc[0];
        if (H == 4)
            mch = (lane & 32) ? ((lane & 16) ? mc[3] : mc[2]) : ((lane & 16) ? mc[1] : mc[0]);
        float mnew = fmaxf(mrun, mch);
        float scale = __expf(mrun - mnew);
        acc0 *= scale; acc1 *= scale; acc2 *= scale; acc3 *= scale; den *= scale;
        mrun = mnew;

        int k = 0;
        for (; k + 4 <= cnt; k += 4) {
            float ea = st[(k + 0) * SW + hd];
            float eb = st[(k + 1) * SW + hd];
            float ec = st[(k + 2) * SW + hd];
            float ed = st[(k + 3) * SW + hd];
            int sa = __float_as_int(st[(k + 0) * SW + SW - 1]);
            int sb = __float_as_int(st[(k + 1) * SW + SW - 1]);
            int sc = __float_as_int(st[(k + 2) * SW + SW - 1]);
            int sd_ = __float_as_int(st[(k + 3) * SW + SW - 1]);
            float pa = __expf(ea - mrun);
            float pb = __expf(eb - mrun);
            float pc = __expf(ec - mrun);
            float pd = __expf(ed - mrun);
            den += (pa + pb) + (pc + pd);
            if (H == 4) {
                if (BF16IN) {
                    uint2 ua = *(const uint2*)&hp[(size_t)sa * 256 + lane * 4];
                    uint2 ub = *(const uint2*)&hp[(size_t)sb * 256 + lane * 4];
                    uint2 uc = *(const uint2*)&hp[(size_t)sc * 256 + lane * 4];
                    uint2 ud = *(const uint2*)&hp[(size_t)sd_ * 256 + lane * 4];
                    acc0 = fmaf(pa, __uint_as_float((ua.x & 0xffffu) << 16), acc0);
                    acc1 = fmaf(pa, __uint_as_float(ua.x & 0xffff0000u), acc1);
                    acc2 = fmaf(pa, __uint_as_float((ua.y & 0xffffu) << 16), acc2);
                    acc3 = fmaf(pa, __uint_as_float(ua.y & 0xffff0000u), acc3);
                    acc0 = fmaf(pb, __uint_as_float((ub.x & 0xffffu) << 16), acc0);
                    acc1 = fmaf(pb, __uint_as_float(ub.x & 0xffff0000u), acc1);
                    acc2 = fmaf(pb, __uint_as_float((ub.y & 0xffffu) << 16), acc2);
                    acc3 = fmaf(pb, __uint_as_float(ub.y & 0xffff0000u), acc3);
                    acc0 = fmaf(pc, __uint_as_float((uc.x & 0xffffu) << 16), acc0);
                    acc1 = fmaf(pc, __uint_as_float(uc.x & 0xffff0000u), acc1);
                    acc2 = fmaf(pc, __uint_as_float((uc.y & 0xffffu) << 16), acc2);
                    acc3 = fmaf(pc, __uint_as_float(uc.y & 0xffff0000u), acc3);
                    acc0 = fmaf(pd, __uint_as_float((ud.x & 0xffffu) << 16), acc0);
                    acc1 = fmaf(pd, __uint_as_float(ud.x & 0xffff0000u), acc1);
                    acc2 = fmaf(pd, __uint_as_float((ud.y & 0xffffu) << 16), acc2);
                    acc3 = fmaf(pd, __uint_as_float(ud.y & 0xffff0000u), acc3);
                } else {
                    float4 ha = *(const float4*)&hf[(size_t)sa * 256 + lane * 4];
                    float4 hb = *(const float4*)&hf[(size_t)sb * 256 + lane * 4];
                    float4 hc = *(const float4*)&hf[(size_t)sc * 256 + lane * 4];
                    float4 hdv = *(const float4*)&hf[(size_t)sd_ * 256 + lane * 4];
                    acc0 = fmaf(pa, ha.x, acc0); acc1 = fmaf(pa, ha.y, acc1);
                    acc2 = fmaf(pa, ha.z, acc2); acc3 = fmaf(pa, ha.w, acc3);
                    acc0 = fmaf(pb, hb.x, acc0); acc1 = fmaf(pb, hb.y, acc1);
                    acc2 = fmaf(pb, hb.z, acc2); acc3 = fmaf(pb, hb.w, acc3);
                    acc0 = fmaf(pc, hc.x, acc0); acc1 = fmaf(pc, hc.y, acc1);
                    acc2 = fmaf(pc, hc.z, acc2); acc3 = fmaf(pc, hc.w, acc3);
                    acc0 = fmaf(pd, hdv.x, acc0); acc1 = fmaf(pd, hdv.y, acc1);
                    acc2 = fmaf(pd, hdv.z, acc2); acc3 = fmaf(pd, hdv.w, acc3);
                }
            } else {
                float ha, hb, hc, hdv;
                if (BF16IN) {
                    ha = bf16_to_f32(hp[(size_t)sa * 64 + lane]);
                    hb = bf16_to_f32(hp[(size_t)sb * 64 + lane]);
                    hc = bf16_to_f32(hp[(size_t)sc * 64 + lane]);
                    hdv = bf16_to_f32(hp[(size_t)sd_ * 64 + lane]);
                } else {
                    ha = hf[(size_t)sa * 64 + lane];
                    hb = hf[(size_t)sb * 64 + lane];
                    hc = hf[(size_t)sc * 64 + lane];
                    hdv = hf[(size_t)sd_ * 64 + lane];
                }
                acc0 = fmaf(pa, ha, acc0);
                acc0 = fmaf(pb, hb, acc0);
                acc0 = fmaf(pc, hc, acc0);
                acc0 = fmaf(pd, hdv, acc0);
            }
        }
        for (; k < cnt; ++k) {
            float e = st[k * SW + hd];
            int src = __float_as_int(st[k * SW + SW - 1]);
            float p = __expf(e - mrun);
            den += p;
            if (H == 4) {
                if (BF16IN) {
                    uint2 uv = *(const uint2*)&hp[(size_t)src * 256 + lane * 4];
                    acc0 = fmaf(p, __uint_as_float((uv.x & 0xffffu) << 16), acc0);
                    acc1 = fmaf(p, __uint_as_float(uv.x & 0xffff0000u), acc1);
                    acc2 = fmaf(p, __uint_as_float((uv.y & 0xffffu) << 16), acc2);
                    acc3 = fmaf(p, __uint_as_float(uv.y & 0xffff0000u), acc3);
                } else {
                    float4 hv = *(const float4*)&hf[(size_t)src * 256 + lane * 4];
                    acc0 = fmaf(p, hv.x, acc0); acc1 = fmaf(p, hv.y, acc1);
                    acc2 = fmaf(p, hv.z, acc2); acc3 = fmaf(p, hv.w, acc3);
                }
            } else {
                float hv = BF16IN ? bf16_to_f32(hp[(size_t)src * 64 + lane])
                                  : hf[(size_t)src * 64 + lane];
                acc0 = fmaf(p, hv, acc0);
            }
        }
    }

    float inv = 1.0f / (den + 1e-16f);
    if (H == 4) {
        float4 bv = *(const float4*)&bias[lane * 4];
        float4 o;
        o.x = elu_f(acc0 * inv + bv.x); o.y = elu_f(acc1 * inv + bv.y);
        o.z = elu_f(acc2 * inv + bv.z); o.w = elu_f(acc3 * inv + bv.w);
        *(float4*)&out[(size_t)node * 256 + lane * 4] = o;
    } else {
        out[(size_t)node * 64 + lane] = elu_f(acc0 * inv + bias[lane]);
    }
}

// ---------- pooling ----------
__global__ void pool_init(float* gsum, unsigned* gmax, int* gcnt) {
    int t = blockIdx.x * blockDim.x + threadIdx.x;
    if (t < NG * 64) { gsum[t] = 0.f; gmax[t] = enc_f32(-INFINITY); }
    if (t < NG) gcnt[t] = 0;
}

__global__ void pool_reduce(const float* __restrict__ h3, const int* __restrict__ batch,
                            float* __restrict__ gsum, unsigned* __restrict__ gmax,
                            int* __restrict__ gcnt, int N, int per) {
    int w = (blockIdx.x * blockDim.x + threadIdx.x) >> 6;
    int lane = threadIdx.x & 63;
    int n0 = w * per;
    int n1 = min(N, n0 + per);
    float lsum = 0.f, lmax = -INFINITY;
    int cur = -1, cnt = 0;
    for (int n = n0; n < n1; ++n) {
        int g = batch[n];
        if (g != cur) {
            if (cur >= 0) {
                atomicAdd(&gsum[cur * 64 + lane], lsum);
                atomicMax(&gmax[cur * 64 + lane], enc_f32(lmax));
                if (lane == 0) atomicAdd(&gcnt[cur], cnt);
            }
            cur = g; lsum = 0.f; lmax = -INFINITY; cnt = 0;
        }
        float v = h3[(size_t)n * 64 + lane];
        lsum += v; lmax = fmaxf(lmax, v); cnt++;
    }
    if (cur >= 0) {
        atomicAdd(&gsum[cur * 64 + lane], lsum);
        atomicMax(&gmax[cur * 64 + lane], enc_f32(lmax));
        if (lane == 0) atomicAdd(&gcnt[cur], cnt);
    }
}

// ---------- classifier: one block per graph ----------
__global__ __launch_bounds__(128) void classifier(const float* __restrict__ gsum,
                                                  const unsigned* __restrict__ gmax,
                                                  const int* __restrict__ gcnt,
                                                  const float* __restrict__ Wc1,
                                                  const float* __restrict__ bc1,
                                                  const float* __restrict__ Wc2,
                                                  const float* __restrict__ bc2,
                                                  float* __restrict__ out) {
    __shared__ float gv[128];
    __shared__ float z1[64];
    int g = blockIdx.x, t = threadIdx.x;
    int cnt = gcnt[g];
    if (t < 64) {
        gv[t] = gsum[g * 64 + t] / fmaxf((float)cnt, 1.f);
    } else {
        float mx = dec_f32(gmax[g * 64 + (t - 64)]);
        gv[t] = (cnt > 0) ? mx : 0.f;
    }
    __syncthreads();
    if (t < 64) {
        float a = bc1[t];
        for (int k = 0; k < 128; ++k) a = fmaf(Wc1[t * 128 + k], gv[k], a);
        z1[t] = a > 0.f ? a : 0.f;
    }
    __syncthreads();
    if (t < 10) {
        float a = bc2[t];
        for (int k = 0; k < 64; ++k) a = fmaf(Wc2[t * 64 + k], z1[k], a);
        out[g * 10 + t] = a;
    }
}

// ---------- launch ----------
extern "C" void kernel_launch(void* const* d_in, const int* in_sizes, int n_in,
                              void* d_out, int out_size, void* d_ws, size_t ws_size,
                              hipStream_t stream) {
    const float* x      = (const float*)d_in[0];
    const int*   ei     = (const int*)d_in[1];
    const int*   batch  = (const int*)d_in[2];
    const float* W_emb  = (const float*)d_in[3];
    const float* b_emb  = (const float*)d_in[4];
    const float* W1     = (const float*)d_in[5];
    const float* as1    = (const float*)d_in[6];
    const float* ad1    = (const float*)d_in[7];
    const float* b1     = (const float*)d_in[8];
    const float* W2     = (const float*)d_in[9];
    const float* as2    = (const float*)d_in[10];
    const float* ad2    = (const float*)d_in[11];
    const float* b2     = (const float*)d_in[12];
    const float* W3     = (const float*)d_in[13];
    const float* as3    = (const float*)d_in[14];
    const float* ad3    = (const float*)d_in[15];
    const float* b3     = (const float*)d_in[16];
    const float* Wc1    = (const float*)d_in[17];
    const float* bc1    = (const float*)d_in[18];
    const float* Wc2    = (const float*)d_in[19];
    const float* bc2    = (const float*)d_in[20];

    const int N = in_sizes[0] / F_IN;   // 50000
    const int E = in_sizes[1] / 2;      // 800000
    const int ET = E + N;

    // workspace carve-up (256B aligned)
    size_t off = 0;
    auto alloc = [&](size_t bytes) -> void* {
        void* p = (char*)d_ws + off;
        off += (bytes + 255) & ~(size_t)255;
        return p;
    };
    float*    A       = (float*)alloc((size_t)N * 64 * 4);    // emb out (f32); later h3 (bf16)
    float*    X       = (float*)alloc((size_t)N * 256 * 4);   // G1 f32; h2 bf16; agg3 out f32
    float*    Y       = (float*)alloc((size_t)N * 256 * 4);   // C1 f32; C2 f32
    float*    S       = (float*)alloc((size_t)N * 4 * 4);
    float*    D       = (float*)alloc((size_t)N * 4 * 4);
    unsigned* Wp_emb  = (unsigned*)alloc(64 * 128 * 4);
    unsigned* Wp1     = (unsigned*)alloc(256 * 64 * 4);
    unsigned* Wp2     = (unsigned*)alloc(256 * 256 * 4);
    unsigned* Wp3     = (unsigned*)alloc(64 * 256 * 4);
    float*    us1     = (float*)alloc(4 * 64 * 4);
    float*    ud1     = (float*)alloc(4 * 64 * 4);
    int*      offs    = (int*)alloc((size_t)(N + 1) * 4);
    int*      cnt     = (int*)alloc((size_t)N * 4);
    int*      bsum    = (int*)alloc(64 * 4);
    int*      csr_src = (int*)alloc((size_t)ET * 4);
    float*    gsum    = (float*)alloc(NG * 64 * 4);
    unsigned* gmax    = (unsigned*)alloc(NG * 64 * 4);
    int*      gcnt    = (int*)alloc(NG * 4);
    (void)ws_size; (void)n_in; (void)out_size;

    const int SCB = (N + 1023) / 1024;

    // weight pre-pack + u-vectors (tiny)
    convert_pack<<<8, 256, 0, stream>>>(W_emb, Wp_emb, 64 * 128);
    convert_pack<<<16, 256, 0, stream>>>(W1, Wp1, 256 * 64);
    convert_pack<<<64, 256, 0, stream>>>(W2, Wp2, 256 * 256);
    convert_pack<<<16, 256, 0, stream>>>(W3, Wp3, 64 * 256);
    uvec_kernel<<<1, 256, 0, stream>>>(W1, as1, ad1, us1, ud1);

    // CSR build
    hipMemsetAsync(cnt, 0, (size_t)N * 4, stream);
    hist_kernel<<<(ET + 255) / 256, 256, 0, stream>>>(ei, cnt, E, N);
    scan1_kernel<<<SCB, 256, 0, stream>>>(cnt, offs, bsum, N);
    scan2_kernel<<<1, 64, 0, stream>>>(bsum, offs, SCB, N);
    scan3_kernel<<<SCB, 256, 0, stream>>>(offs, bsum, N);
    hipMemsetAsync(cnt, 0, (size_t)N * 4, stream);
    scatter_kernel<<<(ET + 255) / 256, 256, 0, stream>>>(ei, offs, cnt, csr_src, E, N);

    const int NWV = (N * 64 + 255) / 256;
    const int GB = (N + 63) / 64;

    // embedding: A = x@W_embT + b_emb (f32), fused s1,d1 via commute u-vectors
    gemm_mfma<128, 64, 4, true, false, false, false><<<dim3(GB, 1), 256, 0, stream>>>(
        x, 128, Wp_emb, A, 64, b_emb, us1, ud1, S, D, N);
    // layer-1 commuted aggregation over raw embeddings (f32)
    gat_agg_x<<<NWV, 256, 0, stream>>>(A, S, D, offs, csr_src, X, N);
    // per-head transform: C1[:,h*64:+64] = elu(G1[:,h,:] @ W1_hT + b1)  (f32 out)
    gemm_mfma<64, 64, 0, false, true, true, false><<<dim3(GB, 4), 256, 0, stream>>>(
        X, 256, Wp1, Y, 256, b1, nullptr, nullptr, nullptr, nullptr, N);
    // layer 2: h2 = C1@W2T -> bf16, fused s2,d2
    gemm_mfma<256, 256, 4, false, false, false, true><<<dim3(GB, 1), 256, 0, stream>>>(
        Y, 256, Wp2, X, 256, nullptr, as2, ad2, S, D, N);
    gat_agg<4, true><<<NWV, 256, 0, stream>>>(X, S, D, offs, csr_src, b2, Y, N);
    // layer 3: h3 = C2@W3T -> bf16, fused s3,d3
    gemm_mfma<256, 64, 1, true, false, false, true><<<dim3(GB, 1), 256, 0, stream>>>(
        Y, 256, Wp3, A, 64, nullptr, as3, ad3, S, D, N);
    gat_agg<1, true><<<NWV, 256, 0, stream>>>(A, S, D, offs, csr_src, b3, X, N);

    // pooling + classifier
    pool_init<<<16, 256, 0, stream>>>(gsum, gmax, gcnt);
    int per = (N + 255) / 256;
    pool_reduce<<<64, 256, 0, stream>>>(X, batch, gsum, gmax, gcnt, N, per);
    classifier<<<NG, 128, 0, stream>>>(gsum, gmax, gcnt, Wc1, bc1, Wc2, bc2, (float*)d_out);
}